// Round 12
// baseline (675.864 us; speedup 1.0000x reference)
//
#include <hip/hip_runtime.h>

typedef unsigned short ushort_t;
typedef unsigned int   uint32;
typedef __attribute__((ext_vector_type(8))) short short8;   // 8 bf16 (4 VGPRs)
typedef __attribute__((ext_vector_type(4))) float f32x4;    // MFMA acc
typedef __attribute__((ext_vector_type(4))) uint32 u32x4;

// ---------------- problem constants ----------------
#define B_     8
#define CIN    512
#define HFM    10
#define WFM    25
#define CF     64
#define NANCH  2784          // N
#define NANCHP 2816          // N padded to 64 (K-tiling)
#define NM     2783          // N-1
#define NMPAD  2816          // N-1 padded (cols for scores)
#define D_     640           // CF*HFM
#define D2     1280
#define ALEN   77
#define M_     (B_*NANCH)    // 22272
#define NO     128           // padded head-output dim (75 used)

__device__ __forceinline__ ushort_t f2bf(float f) {
    uint32 u = __float_as_uint(f);
    u += 0x7fffu + ((u >> 16) & 1u);     // RNE
    return (ushort_t)(u >> 16);
}
__device__ __forceinline__ float bf2f(ushort_t h) {
    return __uint_as_float(((uint32)h) << 16);
}

// ============ 1x1 conv ============
__global__ __launch_bounds__(256) void conv_feat_k(const float* __restrict__ x,
    const float* __restrict__ w, const float* __restrict__ bias,
    float* __restrict__ feat)
{
    int t = blockIdx.x * 256 + threadIdx.x;
    if (t >= B_ * CF * HFM * WFM) return;
    int pos = t % (HFM * WFM);
    int f   = (t / (HFM * WFM)) % CF;
    int b   = t / (CF * HFM * WFM);
    const float* xp = x + (size_t)b * CIN * HFM * WFM + pos;
    const float* wp = w + (size_t)f * CIN;
    float s = bias[f];
#pragma unroll 4
    for (int c = 0; c < CIN; ++c)
        s += xp[(size_t)c * (HFM * WFM)] * wp[c];
    feat[t] = s;
}

// ============ gather -> pf16 [M_][640] ============
__global__ __launch_bounds__(256) void gather_pf_k(const float* __restrict__ feat,
    const int* __restrict__ cut_xs, const unsigned char* __restrict__ invalid,
    ushort_t* __restrict__ pf16)
{
    long long t = (long long)blockIdx.x * 256 + threadIdx.x;
    if (t >= (long long)M_ * D_) return;
    int d = (int)(t % D_);
    int r = (int)(t / D_);
    int n = r % NANCH;
    int b = r / NANCH;
    int f = d / HFM, h = d - f * HFM;
    int idx = n * HFM + h;
    float v = 0.f;
    if (!invalid[idx]) {
        int xs = cut_xs[idx];
        v = feat[((size_t)(b * CF + f) * HFM + h) * WFM + xs];
    }
    pf16[t] = f2bf(v);
}

// ============ attn_w fp32 [2783][640] -> bf16 padded [2816][640] ============
__global__ __launch_bounds__(256) void prep_attn_w_k(const float* __restrict__ attn_w,
    ushort_t* __restrict__ w16)
{
    int t = blockIdx.x * 256 + threadIdx.x;
    if (t >= NMPAD * D_) return;
    int m = t / D_;
    w16[t] = (m < NM) ? f2bf(attn_w[(size_t)m * D_ + (t % D_)]) : (ushort_t)0;
}

// ============ heads weights -> bf16 padded [128][1280] ============
__global__ __launch_bounds__(256) void prep_heads_w_k(const float* __restrict__ cls_w,
    const float* __restrict__ reg_w, ushort_t* __restrict__ w16)
{
    int t = blockIdx.x * 256 + threadIdx.x;
    if (t >= 128 * D2) return;
    int o = t / D2, k = t % D2;
    float v = 0.f;
    if (o < 2)       v = cls_w[(size_t)o * D2 + k];
    else if (o < 75) v = reg_w[(size_t)(o - 2) * D2 + k];
    w16[t] = (o < 75) ? f2bf(v) : (ushort_t)0;
}

// ============ zero Gt K-pad cols [2784..2816) ============
__global__ __launch_bounds__(256) void zero_gtpad_k(ushort_t* __restrict__ Gt)
{
    int t = blockIdx.x * 256 + threadIdx.x;
    if (t >= B_ * NO * 32) return;
    int n = t & 31, o = (t >> 5) & (NO - 1), b = t >> 12;
    Gt[((size_t)b * NO + o) * NANCHP + NANCH + n] = 0;
}

// --------------------------------------------------------------------------
// DIRECT-LOAD MFMA kernels (no LDS, no barriers). Guide Common-mistake #7:
// the operands are L2-resident (FETCH 80MB vs 1.25GB staged in R11 = 94%
// L2-hit) -- LDS staging was pure overhead, and its barrier coupling was the
// measured ~1.2k cyc/iter wall (R7-R11). The MFMA fragment pattern
// (lane=q*16+cl -> 16 rows x 64B) is itself fully coalesced as a direct
// global load (64 lanes x 16B = 16 whole cache lines). Waves are now fully
// independent pipelines; compiler schedules loads across iters freely.
// --------------------------------------------------------------------------

// ============ scores+exp MFMA: E[r][m+(m>=n)] = bf16(exp(pf·attn_w^T + attn_b)) ============
// exp without max-subtraction is safe: scores sigma ~= 0.06 (pf~0.23 x w~0.01 x K=640).
// Also writes E's K-pad cols (colb 21) and diagonal zeros (owning colb) -- no zero_epad pass.
__global__ __launch_bounds__(256, 4) void scores_mfma_k(
    const ushort_t* __restrict__ A,   // pf16 [M_][640]
    const ushort_t* __restrict__ Bw,  // attnw16 [2816][640]
    const float* __restrict__ attn_b,
    ushort_t* __restrict__ E)         // E [M_+32][2816], unnormalized exp bf16
{
    // grid 3828 = 174 rowslabs x 22 colslabs; bijective XCD chunk (q=478,r=4)
    const int orig = blockIdx.x;
    const int xcd = orig & 7, pos = orig >> 3;
    const int start = (xcd < 4) ? xcd * 479 : 1916 + (xcd - 4) * 478;
    const int idx = start + pos;
    const int rowb = idx / 22, colb = idx - rowb * 22;
    const int row0 = rowb * 128, col0 = colb * 128;
    const int t = threadIdx.x;
    const int wid = t >> 6, lane = t & 63;
    const int wr = wid >> 1, wc = wid & 1;          // 2x2 wave grid, 64x64 each
    const int cl = lane & 15, q = lane >> 4;
    const ushort_t* pa[4];
    const ushort_t* pb[4];
#pragma unroll
    for (int i = 0; i < 4; ++i) {
        pa[i] = A  + (size_t)(row0 + wr * 64 + i * 16 + cl) * D_ + q * 8;
        pb[i] = Bw + (size_t)(col0 + wc * 64 + i * 16 + cl) * D_ + q * 8;
    }
    f32x4 acc[4][4];
#pragma unroll
    for (int i = 0; i < 4; ++i)
#pragma unroll
        for (int j = 0; j < 4; ++j) acc[i][j] = (f32x4){0.f, 0.f, 0.f, 0.f};

#pragma unroll 4
    for (int k0 = 0; k0 < D_; k0 += 32) {
        short8 af[4], bv[4];
#pragma unroll
        for (int i = 0; i < 4; ++i) af[i] = *(const short8*)(pa[i] + k0);
#pragma unroll
        for (int j = 0; j < 4; ++j) bv[j] = *(const short8*)(pb[j] + k0);
#pragma unroll
        for (int i = 0; i < 4; ++i)
#pragma unroll
            for (int j = 0; j < 4; ++j)
                acc[i][j] = __builtin_amdgcn_mfma_f32_16x16x32_bf16(af[i], bv[j], acc[i][j], 0, 0, 0);
    }

#pragma unroll
    for (int i = 0; i < 4; ++i) {
#pragma unroll
        for (int ee = 0; ee < 4; ++ee) {
            int r = row0 + wr * 64 + i * 16 + q * 4 + ee;
            int n = r % NANCH;
            ushort_t* orow = E + (size_t)r * NANCHP;
#pragma unroll
            for (int j = 0; j < 4; ++j) {
                int m = col0 + wc * 64 + j * 16 + cl;
                if (m < NM) orow[m + (m >= n)] = f2bf(__expf(acc[i][j][ee] + attn_b[m]));
                else if (m < NMPAD - 1) orow[m + 1] = 0;    // K-pad cols 2784..2815
            }
            int dc = n - (col0 + wc * 64);                   // diagonal zero
            if (dc >= 0 && dc < 64 && (dc & 15) == cl) orow[n] = 0;
        }
    }
}

// ============ normalize (vectorized, G13): attn[r][:] = E/sum (fp32); rsum[r] = sum ============
__global__ __launch_bounds__(256) void normalize_k(const ushort_t* __restrict__ E,
    float* __restrict__ attn, float* __restrict__ rsum)
{
    const int r = blockIdx.x;
    float* row = attn + (size_t)r * NANCH;
    const ushort_t* row16 = E + (size_t)r * NANCHP;
    const int t = threadIdx.x;
    __shared__ float red[4];
    float vals[16];                           // static-indexed -> VGPRs
    float s = 0.f;
#pragma unroll
    for (int i = 0; i < 2; ++i) {             // 348 short8-chunks per row (2784 = 348*8)
        int c = t + i * 256;
        float v0 = 0.f, v1 = 0.f, v2 = 0.f, v3 = 0.f, v4 = 0.f, v5 = 0.f, v6 = 0.f, v7 = 0.f;
        if (c < 348) {
            u32x4 u = *(const u32x4*)&row16[8 * c];   // 16B load: 8 bf16
            v0 = bf2f((ushort_t)(u.x & 0xffffu)); v1 = bf2f((ushort_t)(u.x >> 16));
            v2 = bf2f((ushort_t)(u.y & 0xffffu)); v3 = bf2f((ushort_t)(u.y >> 16));
            v4 = bf2f((ushort_t)(u.z & 0xffffu)); v5 = bf2f((ushort_t)(u.z >> 16));
            v6 = bf2f((ushort_t)(u.w & 0xffffu)); v7 = bf2f((ushort_t)(u.w >> 16));
        }
        vals[8 * i + 0] = v0; vals[8 * i + 1] = v1; vals[8 * i + 2] = v2; vals[8 * i + 3] = v3;
        vals[8 * i + 4] = v4; vals[8 * i + 5] = v5; vals[8 * i + 6] = v6; vals[8 * i + 7] = v7;
        s += ((v0 + v1) + (v2 + v3)) + ((v4 + v5) + (v6 + v7));
    }
    for (int off = 32; off; off >>= 1) s += __shfl_down(s, off);
    if ((t & 63) == 0) red[t >> 6] = s;
    __syncthreads();
    s = red[0] + red[1] + red[2] + red[3];
    float inv = 1.0f / s;
    if (t == 0) rsum[r] = s;
#pragma unroll
    for (int i = 0; i < 2; ++i) {
        int c = t + i * 256;
        if (c < 348) {
            float4 w0 = make_float4(vals[8 * i] * inv, vals[8 * i + 1] * inv,
                                    vals[8 * i + 2] * inv, vals[8 * i + 3] * inv);
            float4 w1 = make_float4(vals[8 * i + 4] * inv, vals[8 * i + 5] * inv,
                                    vals[8 * i + 6] * inv, vals[8 * i + 7] * inv);
            *(float4*)&row[8 * c]     = w0;   // 32B stores, 16B-aligned
            *(float4*)&row[8 * c + 4] = w1;
        }
    }
}

// ============ Gt[b][o][n] = (pf·W1^T)[n][o]  (W1 = hw16 cols 0..639), direct-load ============
__global__ __launch_bounds__(256, 4) void gx_mfma_k(
    const ushort_t* __restrict__ A,   // pf16 [M_][640]
    const ushort_t* __restrict__ W,   // hw16 [128][1280]
    ushort_t* __restrict__ Gt)        // [B][128][2816]
{
    const int row0 = blockIdx.x * 128;
    const int t = threadIdx.x;
    const int wid = t >> 6, lane = t & 63;
    const int wr = wid >> 1, wc = wid & 1;
    const int cl = lane & 15, q = lane >> 4;
    const ushort_t* pa[4];
    const ushort_t* pb[4];
#pragma unroll
    for (int i = 0; i < 4; ++i) {
        pa[i] = A + (size_t)(row0 + wr * 64 + i * 16 + cl) * D_ + q * 8;
        pb[i] = W + (size_t)(wc * 64 + i * 16 + cl) * D2 + q * 8;
    }
    f32x4 acc[4][4];
#pragma unroll
    for (int i = 0; i < 4; ++i)
#pragma unroll
        for (int j = 0; j < 4; ++j) acc[i][j] = (f32x4){0.f, 0.f, 0.f, 0.f};

#pragma unroll 4
    for (int k0 = 0; k0 < D_; k0 += 32) {
        short8 af[4], bv[4];
#pragma unroll
        for (int i = 0; i < 4; ++i) af[i] = *(const short8*)(pa[i] + k0);
#pragma unroll
        for (int j = 0; j < 4; ++j) bv[j] = *(const short8*)(pb[j] + k0);
#pragma unroll
        for (int i = 0; i < 4; ++i)
#pragma unroll
            for (int j = 0; j < 4; ++j)
                acc[i][j] = __builtin_amdgcn_mfma_f32_16x16x32_bf16(af[i], bv[j], acc[i][j], 0, 0, 0);
    }

#pragma unroll
    for (int i = 0; i < 4; ++i) {
#pragma unroll
        for (int ee = 0; ee < 4; ++ee) {
            int r = row0 + wr * 64 + i * 16 + q * 4 + ee;   // < M_ (174*128 exact)
            int b = r / NANCH, nl = r - b * NANCH;
#pragma unroll
            for (int j = 0; j < 4; ++j) {
                int o = wc * 64 + j * 16 + cl;
                Gt[((size_t)b * NO + o) * NANCHP + nl] = f2bf(acc[i][j][ee]);
            }
        }
    }
}

// ============ final (split-K x5, direct-load): kc 0..3 = E·G1, kc 4 = pf·W2^T ============
__global__ __launch_bounds__(256, 4) void final_mfma_k(
    const ushort_t* __restrict__ E16,  // E [M_+32][2816] (unnormalized exp)
    const ushort_t* __restrict__ pf16, // [M_][640]
    const ushort_t* __restrict__ Gt,   // [B][128][2816]
    const ushort_t* __restrict__ W,    // hw16 [128][1280] (W2 = cols 640..1279)
    float* __restrict__ part)          // [5][M_][128] fp32 partials
{
    // grid 880: b=XCD (Gt[b] L2-resident), rb=row-slab 0..21, kc=chunk 0..4
    const int b = blockIdx.x & 7;
    const int u = blockIdx.x >> 3;
    const int rb = u % 22, kc = u / 22;
    const int t = threadIdx.x;
    const int wid = t >> 6, lane = t & 63;
    const int wr = wid >> 1, wc = wid & 1;
    const int cl = lane & 15, q = lane >> 4;
    // A rows may over-read past batch end (E has +32-row pad; pf16 over-read
    // lands in aw16) -> finite bits, row-independent, discarded at write.
    f32x4 acc[4][4];
#pragma unroll
    for (int i = 0; i < 4; ++i)
#pragma unroll
        for (int j = 0; j < 4; ++j) acc[i][j] = (f32x4){0.f, 0.f, 0.f, 0.f};

    if (kc < 4) {                               // E·G1 over K-tiles [kc*22, kc*22+22)
        const int k0b = kc * 22 * 32;
        const ushort_t* pa[4];
        const ushort_t* pb[4];
#pragma unroll
        for (int i = 0; i < 4; ++i) {
            pa[i] = E16 + ((size_t)b * NANCH + rb * 128 + wr * 64 + i * 16 + cl) * NANCHP + k0b + q * 8;
            pb[i] = Gt  + ((size_t)b * NO + wc * 64 + i * 16 + cl) * NANCHP + k0b + q * 8;
        }
#pragma unroll 4
        for (int k0 = 0; k0 < 22 * 32; k0 += 32) {
            short8 af[4], bv[4];
#pragma unroll
            for (int i = 0; i < 4; ++i) af[i] = *(const short8*)(pa[i] + k0);
#pragma unroll
            for (int j = 0; j < 4; ++j) bv[j] = *(const short8*)(pb[j] + k0);
#pragma unroll
            for (int i = 0; i < 4; ++i)
#pragma unroll
                for (int j = 0; j < 4; ++j)
                    acc[i][j] = __builtin_amdgcn_mfma_f32_16x16x32_bf16(af[i], bv[j], acc[i][j], 0, 0, 0);
        }
    } else {                                    // pf·W2^T over K = 640
        const ushort_t* pa[4];
        const ushort_t* pb[4];
#pragma unroll
        for (int i = 0; i < 4; ++i) {
            pa[i] = pf16 + ((size_t)b * NANCH + rb * 128 + wr * 64 + i * 16 + cl) * D_ + q * 8;
            pb[i] = W + (size_t)(wc * 64 + i * 16 + cl) * D2 + D_ + q * 8;
        }
#pragma unroll 4
        for (int k0 = 0; k0 < D_; k0 += 32) {
            short8 af[4], bv[4];
#pragma unroll
            for (int i = 0; i < 4; ++i) af[i] = *(const short8*)(pa[i] + k0);
#pragma unroll
            for (int j = 0; j < 4; ++j) bv[j] = *(const short8*)(pb[j] + k0);
#pragma unroll
            for (int i = 0; i < 4; ++i)
#pragma unroll
                for (int j = 0; j < 4; ++j)
                    acc[i][j] = __builtin_amdgcn_mfma_f32_16x16x32_bf16(af[i], bv[j], acc[i][j], 0, 0, 0);
        }
    }

    float* pout = part + (size_t)kc * M_ * NO;
#pragma unroll
    for (int i = 0; i < 4; ++i) {
#pragma unroll
        for (int ee = 0; ee < 4; ++ee) {
            int nl = rb * 128 + wr * 64 + i * 16 + q * 4 + ee;
            if (nl < NANCH) {
                int r = b * NANCH + nl;
#pragma unroll
                for (int j = 0; j < 4; ++j) {
                    int oo = wc * 64 + j * 16 + cl;
                    pout[(size_t)r * NO + oo] = acc[i][j][ee];
                }
            }
        }
    }
}

// ============ reduce: out = (p0+p1+p2+p3)/rsum + p4 + bias; heads epilogue ============
__global__ __launch_bounds__(256) void reduce_heads_k(
    const float* __restrict__ part,    // [5][M_][128]
    const float* __restrict__ rsum,
    const float* __restrict__ cls_b, const float* __restrict__ reg_b,
    const float* __restrict__ anchors,
    float* __restrict__ cls_out, float* __restrict__ lanes)
{
    int t = blockIdx.x * 256 + threadIdx.x;
    if (t >= M_ * 80) return;
    int r = t / 80, oo = t - r * 80;
    int nl = r % NANCH;
    if (oo < 75) {
        float inv = 1.0f / rsum[r];
        size_t base = (size_t)r * NO + oo, st = (size_t)M_ * NO;
        float v = ((part[base] + part[base + st]) + (part[base + 2 * st] + part[base + 3 * st])) * inv
                + part[base + 4 * st];
        if (oo < 2) {
            cls_out[(size_t)r * 2 + oo] = v + cls_b[oo];
        } else {
            int qq = oo - 2;
            int c = 4 + qq;
            float res = v + reg_b[qq];
            if (qq > 0) res += anchors[(size_t)nl * ALEN + c];
            lanes[(size_t)r * ALEN + c] = res;
        }
    } else if (oo < 79) {
        int c = oo - 75;                      // lanes cols 0..3 = anchors
        lanes[(size_t)r * ALEN + c] = anchors[(size_t)nl * ALEN + c];
    }
}

extern "C" void kernel_launch(void* const* d_in, const int* in_sizes, int n_in,
                              void* d_out, int out_size, void* d_ws, size_t ws_size,
                              hipStream_t stream)
{
    (void)in_sizes; (void)n_in; (void)out_size; (void)ws_size;
    const float* x       = (const float*)d_in[0];
    const float* conv_w  = (const float*)d_in[1];
    const float* conv_b  = (const float*)d_in[2];
    const float* attn_w  = (const float*)d_in[3];
    const float* attn_b  = (const float*)d_in[4];
    const float* cls_w   = (const float*)d_in[5];
    const float* cls_b   = (const float*)d_in[6];
    const float* reg_w   = (const float*)d_in[7];
    const float* reg_b   = (const float*)d_in[8];
    const float* anchors = (const float*)d_in[9];
    const int*   cut_xs  = (const int*)d_in[10];
    const unsigned char* invalid = (const unsigned char*)d_in[11];

    float* out     = (float*)d_out;
    float* cls_out = out;
    float* lanes   = out + (size_t)M_ * 2;
    float* attn    = out + (size_t)M_ * 2 + (size_t)M_ * ALEN;

    // workspace layout (~222 MB)
    char* w = (char*)d_ws;
    float* feat      = (float*)w;    w += (size_t)B_ * CF * HFM * WFM * 4;       // 512 KB
    ushort_t* pf16   = (ushort_t*)w; w += (size_t)M_ * D_ * 2;                   // 28.5 MB
    ushort_t* aw16   = (ushort_t*)w; w += (size_t)NMPAD * D_ * 2;                // 3.6 MB (absorbs pf16 over-read)
    ushort_t* hw16   = (ushort_t*)w; w += (size_t)128 * D2 * 2;                  // 320 KB
    ushort_t* Gt     = (ushort_t*)w; w += (size_t)B_ * NO * NANCHP * 2;          // 5.8 MB
    float* part      = (float*)w;    w += (size_t)5 * M_ * NO * 4;               // 57 MB
    float* rsum      = (float*)w;    w += (size_t)M_ * 4;                        // 89 KB
    ushort_t* E16    = (ushort_t*)w; w += (size_t)(M_ + 32) * NANCHP * 2;        // 125.6 MB

    conv_feat_k<<<(B_ * CF * HFM * WFM + 255) / 256, 256, 0, stream>>>(x, conv_w, conv_b, feat);
    gather_pf_k<<<(int)(((long long)M_ * D_ + 255) / 256), 256, 0, stream>>>(feat, cut_xs, invalid, pf16);
    prep_attn_w_k<<<(NMPAD * D_ + 255) / 256, 256, 0, stream>>>(attn_w, aw16);
    prep_heads_w_k<<<(128 * D2 + 255) / 256, 256, 0, stream>>>(cls_w, reg_w, hw16);

    gx_mfma_k<<<M_ / 128, 256, 0, stream>>>(pf16, hw16, Gt);
    zero_gtpad_k<<<(B_ * NO * 32 + 255) / 256, 256, 0, stream>>>(Gt);

    scores_mfma_k<<<dim3(174 * 22), 256, 0, stream>>>(pf16, aw16, attn_b, E16);
    normalize_k<<<M_, 256, 0, stream>>>(E16, attn, rsum);

    final_mfma_k<<<dim3(5 * 22 * B_), 256, 0, stream>>>(E16, pf16, Gt, hw16, part);
    reduce_heads_k<<<(M_ * 80 + 255) / 256, 256, 0, stream>>>(part, rsum, cls_b, reg_b,
                                                              anchors, cls_out, lanes);
}

// Round 13
// 477.504 us; speedup vs baseline: 1.4154x; 1.4154x over previous
//
#include <hip/hip_runtime.h>

typedef unsigned short ushort_t;
typedef unsigned int   uint32;
typedef __attribute__((ext_vector_type(8))) short short8;   // 8 bf16 (4 VGPRs)
typedef __attribute__((ext_vector_type(4))) float f32x4;    // MFMA acc
typedef __attribute__((ext_vector_type(4))) uint32 u32x4;

// ---------------- problem constants ----------------
#define B_     8
#define CIN    512
#define HFM    10
#define WFM    25
#define CF     64
#define NANCH  2784          // N
#define NANCHP 2816          // N padded to 64 (K-tiling)
#define NM     2783          // N-1
#define NMPAD  2816          // N-1 padded (cols for scores)
#define D_     640           // CF*HFM
#define D2     1280
#define ALEN   77
#define M_     (B_*NANCH)    // 22272
#define NO     128           // padded head-output dim (75 used)

#define VMCNT(N)   asm volatile("s_waitcnt vmcnt(" #N ")" ::: "memory")
#define LGKMCNT0() do { asm volatile("s_waitcnt lgkmcnt(0)" ::: "memory"); \
                        __builtin_amdgcn_sched_barrier(0); } while (0)
#define S_BARRIER() do { __builtin_amdgcn_s_barrier(); __builtin_amdgcn_sched_barrier(0); } while (0)

__device__ __forceinline__ ushort_t f2bf(float f) {
    uint32 u = __float_as_uint(f);
    u += 0x7fffu + ((u >> 16) & 1u);     // RNE
    return (ushort_t)(u >> 16);
}
__device__ __forceinline__ float bf2f(ushort_t h) {
    return __uint_as_float(((uint32)h) << 16);
}

__device__ __forceinline__ void gload16(const ushort_t* g, ushort_t* l) {
    __builtin_amdgcn_global_load_lds(
        (const __attribute__((address_space(1))) void*)g,
        (__attribute__((address_space(3))) void*)l, 16, 0, 0);
}

// ============ 1x1 conv ============
__global__ __launch_bounds__(256) void conv_feat_k(const float* __restrict__ x,
    const float* __restrict__ w, const float* __restrict__ bias,
    float* __restrict__ feat)
{
    int t = blockIdx.x * 256 + threadIdx.x;
    if (t >= B_ * CF * HFM * WFM) return;
    int pos = t % (HFM * WFM);
    int f   = (t / (HFM * WFM)) % CF;
    int b   = t / (CF * HFM * WFM);
    const float* xp = x + (size_t)b * CIN * HFM * WFM + pos;
    const float* wp = w + (size_t)f * CIN;
    float s = bias[f];
#pragma unroll 4
    for (int c = 0; c < CIN; ++c)
        s += xp[(size_t)c * (HFM * WFM)] * wp[c];
    feat[t] = s;
}

// ============ gather -> pf16 [M_][640] ============
__global__ __launch_bounds__(256) void gather_pf_k(const float* __restrict__ feat,
    const int* __restrict__ cut_xs, const unsigned char* __restrict__ invalid,
    ushort_t* __restrict__ pf16)
{
    long long t = (long long)blockIdx.x * 256 + threadIdx.x;
    if (t >= (long long)M_ * D_) return;
    int d = (int)(t % D_);
    int r = (int)(t / D_);
    int n = r % NANCH;
    int b = r / NANCH;
    int f = d / HFM, h = d - f * HFM;
    int idx = n * HFM + h;
    float v = 0.f;
    if (!invalid[idx]) {
        int xs = cut_xs[idx];
        v = feat[((size_t)(b * CF + f) * HFM + h) * WFM + xs];
    }
    pf16[t] = f2bf(v);
}

// ============ attn_w fp32 [2783][640] -> bf16 padded [2816][640] ============
__global__ __launch_bounds__(256) void prep_attn_w_k(const float* __restrict__ attn_w,
    ushort_t* __restrict__ w16)
{
    int t = blockIdx.x * 256 + threadIdx.x;
    if (t >= NMPAD * D_) return;
    int m = t / D_;
    w16[t] = (m < NM) ? f2bf(attn_w[(size_t)m * D_ + (t % D_)]) : (ushort_t)0;
}

// ============ heads weights -> bf16 padded [128][1280] ============
__global__ __launch_bounds__(256) void prep_heads_w_k(const float* __restrict__ cls_w,
    const float* __restrict__ reg_w, ushort_t* __restrict__ w16)
{
    int t = blockIdx.x * 256 + threadIdx.x;
    if (t >= 128 * D2) return;
    int o = t / D2, k = t % D2;
    float v = 0.f;
    if (o < 2)       v = cls_w[(size_t)o * D2 + k];
    else if (o < 75) v = reg_w[(size_t)(o - 2) * D2 + k];
    w16[t] = (o < 75) ? f2bf(v) : (ushort_t)0;
}

// ============ zero Gt K-pad cols [2784..2816) ============
__global__ __launch_bounds__(256) void zero_gtpad_k(ushort_t* __restrict__ Gt)
{
    int t = blockIdx.x * 256 + threadIdx.x;
    if (t >= B_ * NO * 32) return;
    int n = t & 31, o = (t >> 5) & (NO - 1), b = t >> 12;
    Gt[((size_t)b * NO + o) * NANCHP + NANCH + n] = 0;
}

// ============ zero E diag + K-pad cols (scores never writes these) ============
__global__ __launch_bounds__(256) void zero_epad_k(ushort_t* __restrict__ E)
{
    int t = blockIdx.x * 256 + threadIdx.x;
    if (t < M_) {
        E[(size_t)t * NANCHP + (t % NANCH)] = 0;            // diagonal
    } else if (t < M_ * 17) {
        int idx = t - M_;
        int r = idx >> 4, w = idx & 15;
        *(uint32*)&E[(size_t)r * NANCHP + NANCH + 2 * w] = 0;  // pad cols
    }
}

// --------------------------------------------------------------------------
// scores: BARRIER-FREE per-wave-private LDS MFMA.
//   R11 lesson: gload_lds async staging is right (R12's direct-load spilled:
//   WRITE 122->224MB, 154->373us). R12 lesson: the block-wide barrier
//   coupling (2/iter x 4-wave lockstep) was R7-R11's ~1.2k cyc/iter wall.
//   Synthesis: each wave owns a PRIVATE 64x64 operand set (A 64x32 + B 64x32
//   = 8KB/buf, dbuf = 16KB/wave, 64KB/block) -> zero cross-wave sharing ->
//   ZERO barriers. Within-wave in-order vmcnt(8) is the only sync;
//   lgkmcnt(0) before overwrite closes the ds_read-vs-DMA-write hazard.
//   8 independent wave-pipelines/CU (R7->R11 law: throughput ~ groups).
//   Chunk-XOR layout (validated R3+): slot l&3 of row j*16+(l>>2) holds
//   chunk (l&3)^((row>>1)&3); linear gload dest == swizzled layout (identity
//   l*8 = (l>>2)*32+(l&3)*8). Read: co = (q ^ ((cl>>1)&3))*8, conflict-free.
// --------------------------------------------------------------------------

// ============ scores+exp MFMA: E[r][m+(m>=n)] = bf16(exp(pf·attn_w^T + attn_b)) ============
// exp without max-subtraction is safe: scores sigma ~= 0.06 (pf~0.23 x w~0.01 x K=640).
__global__ __launch_bounds__(256, 2) void scores_mfma_k(
    const ushort_t* __restrict__ A,   // pf16 [M_][640]
    const ushort_t* __restrict__ Bw,  // attnw16 [2816][640]
    const float* __restrict__ attn_b,
    ushort_t* __restrict__ E)         // E [M_+32][2816], unnormalized exp bf16
{
    __shared__ __align__(16) ushort_t LB[4][2][4096];   // [wave][buf][A 0..2047 | B 2048..4095]
    // grid 3828 = 174 rowslabs x 22 colslabs; bijective XCD chunk (q=478,r=4)
    const int orig = blockIdx.x;
    const int xcd = orig & 7, pos = orig >> 3;
    const int start = (xcd < 4) ? xcd * 479 : 1916 + (xcd - 4) * 478;
    const int idx = start + pos;
    const int rowb = idx / 22, colb = idx - rowb * 22;
    const int row0 = rowb * 128, col0 = colb * 128;
    const int t = threadIdx.x;
    const int wid = t >> 6, lane = t & 63;
    const int wr = wid >> 1, wc = wid & 1;          // 2x2 wave grid, 64x64 each
    const int cl = lane & 15, q = lane >> 4;
    const int srow = lane >> 2;                      // 16 rows per gload instr
    const int swk  = (((lane & 3) ^ ((lane >> 3) & 3)) * 8);
    const ushort_t* gA = A  + (size_t)(row0 + wr * 64 + srow) * D_ + swk;
    const ushort_t* gB = Bw + (size_t)(col0 + wc * 64 + srow) * D_ + swk;
    f32x4 acc[4][4];
#pragma unroll
    for (int i = 0; i < 4; ++i)
#pragma unroll
        for (int j = 0; j < 4; ++j) acc[i][j] = (f32x4){0.f, 0.f, 0.f, 0.f};
    const int co = ((q ^ ((cl >> 1) & 3)) * 8);      // read-slot for chunk q of row i*16+cl

    auto STAGE = [&](int buf, int k0) {              // wave-private: no barrier needed
        ushort_t* pA = &LB[wid][buf][0];
        ushort_t* pB = &LB[wid][buf][2048];
#pragma unroll
        for (int j = 0; j < 4; ++j) {
            gload16(gA + k0 + (size_t)(j * 16) * D_, pA + j * 512);
            gload16(gB + k0 + (size_t)(j * 16) * D_, pB + j * 512);
        }
    };
    auto COMPUTE = [&](int buf) {
        short8 af[4], bv[4];
#pragma unroll
        for (int i = 0; i < 4; ++i) af[i] = *(const short8*)&LB[wid][buf][(i * 16 + cl) * 32 + co];
#pragma unroll
        for (int j = 0; j < 4; ++j) bv[j] = *(const short8*)&LB[wid][buf][2048 + (j * 16 + cl) * 32 + co];
        __builtin_amdgcn_s_setprio(1);
#pragma unroll
        for (int i = 0; i < 4; ++i)
#pragma unroll
            for (int j = 0; j < 4; ++j)
                acc[i][j] = __builtin_amdgcn_mfma_f32_16x16x32_bf16(af[i], bv[j], acc[i][j], 0, 0, 0);
        __builtin_amdgcn_s_setprio(0);
    };

    const int NT = D_ / 32;                 // 20
    STAGE(0, 0); STAGE(1, 32);              // 16 loads outstanding
    int cur = 0;
    for (int tl = 0; tl < NT - 1; ++tl) {
        VMCNT(8);                           // tile tl landed; tile tl+1's 8 in flight
        COMPUTE(cur);
        LGKMCNT0();                         // ds_reads done -> safe to overwrite buf
        if (tl + 2 < NT) STAGE(cur, (tl + 2) * 32);
        cur ^= 1;
    }
    VMCNT(0);
    COMPUTE(cur);

#pragma unroll
    for (int i = 0; i < 4; ++i) {
#pragma unroll
        for (int ee = 0; ee < 4; ++ee) {
            int r = row0 + wr * 64 + i * 16 + q * 4 + ee;
            int n = r % NANCH;
            ushort_t* orow = E + (size_t)r * NANCHP;
#pragma unroll
            for (int j = 0; j < 4; ++j) {
                int m = col0 + wc * 64 + j * 16 + cl;
                if (m < NM) orow[m + (m >= n)] = f2bf(__expf(acc[i][j][ee] + attn_b[m]));
            }
        }
    }
}

// ============ normalize (vectorized, G13): attn[r][:] = E/sum (fp32); rsum[r] = sum ============
__global__ __launch_bounds__(256) void normalize_k(const ushort_t* __restrict__ E,
    float* __restrict__ attn, float* __restrict__ rsum)
{
    const int r = blockIdx.x;
    float* row = attn + (size_t)r * NANCH;
    const ushort_t* row16 = E + (size_t)r * NANCHP;
    const int t = threadIdx.x;
    __shared__ float red[4];
    float vals[16];                           // static-indexed -> VGPRs
    float s = 0.f;
#pragma unroll
    for (int i = 0; i < 2; ++i) {             // 348 short8-chunks per row (2784 = 348*8)
        int c = t + i * 256;
        float v0 = 0.f, v1 = 0.f, v2 = 0.f, v3 = 0.f, v4 = 0.f, v5 = 0.f, v6 = 0.f, v7 = 0.f;
        if (c < 348) {
            u32x4 u = *(const u32x4*)&row16[8 * c];   // 16B load: 8 bf16
            v0 = bf2f((ushort_t)(u.x & 0xffffu)); v1 = bf2f((ushort_t)(u.x >> 16));
            v2 = bf2f((ushort_t)(u.y & 0xffffu)); v3 = bf2f((ushort_t)(u.y >> 16));
            v4 = bf2f((ushort_t)(u.z & 0xffffu)); v5 = bf2f((ushort_t)(u.z >> 16));
            v6 = bf2f((ushort_t)(u.w & 0xffffu)); v7 = bf2f((ushort_t)(u.w >> 16));
        }
        vals[8 * i + 0] = v0; vals[8 * i + 1] = v1; vals[8 * i + 2] = v2; vals[8 * i + 3] = v3;
        vals[8 * i + 4] = v4; vals[8 * i + 5] = v5; vals[8 * i + 6] = v6; vals[8 * i + 7] = v7;
        s += ((v0 + v1) + (v2 + v3)) + ((v4 + v5) + (v6 + v7));
    }
    for (int off = 32; off; off >>= 1) s += __shfl_down(s, off);
    if ((t & 63) == 0) red[t >> 6] = s;
    __syncthreads();
    s = red[0] + red[1] + red[2] + red[3];
    float inv = 1.0f / s;
    if (t == 0) rsum[r] = s;
#pragma unroll
    for (int i = 0; i < 2; ++i) {
        int c = t + i * 256;
        if (c < 348) {
            float4 w0 = make_float4(vals[8 * i] * inv, vals[8 * i + 1] * inv,
                                    vals[8 * i + 2] * inv, vals[8 * i + 3] * inv);
            float4 w1 = make_float4(vals[8 * i + 4] * inv, vals[8 * i + 5] * inv,
                                    vals[8 * i + 6] * inv, vals[8 * i + 7] * inv);
            *(float4*)&row[8 * c]     = w0;   // 32B stores, 16B-aligned
            *(float4*)&row[8 * c + 4] = w1;
        }
    }
}

// ============ Gt[b][o][n] = (pf·W1^T)[n][o]  (W1 = hw16 cols 0..639)  [R11 form] ============
__global__ __launch_bounds__(256, 2) void gx_mfma_k(
    const ushort_t* __restrict__ A,   // pf16 [M_][640]
    const ushort_t* __restrict__ W,   // hw16 [128][1280]
    ushort_t* __restrict__ Gt)        // [B][128][2816]
{
    __shared__ __align__(16) ushort_t As[2][8192];
    __shared__ __align__(16) ushort_t Bs[2][8192];
    const int t = threadIdx.x;
    const int wid = t >> 6, lane = t & 63;
    const int wr = wid >> 1, wc = wid & 1;          // 2x2 wave grid
    const int row0 = blockIdx.x * 128;
    const int r8 = lane >> 3;
    const int ck = (lane & 7) ^ r8;
    const ushort_t* gA = A + (size_t)(row0 + wid * 8 + r8) * D_ + ck * 8;
    const ushort_t* gB = W + (size_t)(wid * 8 + r8) * D2 + ck * 8;
    f32x4 acc[4][4];
#pragma unroll
    for (int i = 0; i < 4; ++i)
#pragma unroll
        for (int j = 0; j < 4; ++j) acc[i][j] = (f32x4){0.f, 0.f, 0.f, 0.f};
    const int cl = lane & 15, q = lane >> 4, cl7 = lane & 7;

    auto STAGE = [&](int buf, int k0) {
        ushort_t* la = &As[buf][wid * 512];
        ushort_t* lb = &Bs[buf][wid * 512];
#pragma unroll
        for (int j = 0; j < 4; ++j) {
            gload16(gA + k0 + (size_t)j * 32 * D_, la + j * 2048);
            gload16(gB + k0 + (size_t)j * 32 * D2, lb + j * 2048);
        }
    };
    auto COMPUTE = [&](int buf) {
#pragma unroll
        for (int ks = 0; ks < 2; ++ks) {
            short8 af[4], bv[4];
            const int co = ((ks * 4 + q) ^ cl7) * 8;
#pragma unroll
            for (int i = 0; i < 4; ++i)
                af[i] = *(const short8*)&As[buf][(wr * 64 + i * 16 + cl) * 64 + co];
#pragma unroll
            for (int j = 0; j < 4; ++j)
                bv[j] = *(const short8*)&Bs[buf][(wc * 64 + j * 16 + cl) * 64 + co];
            __builtin_amdgcn_s_setprio(1);
#pragma unroll
            for (int i = 0; i < 4; ++i)
#pragma unroll
                for (int j = 0; j < 4; ++j)
                    acc[i][j] = __builtin_amdgcn_mfma_f32_16x16x32_bf16(af[i], bv[j], acc[i][j], 0, 0, 0);
            __builtin_amdgcn_s_setprio(0);
        }
    };

    const int NT = D_ / 64;                 // 10
    STAGE(0, 0); STAGE(1, 64);
    int cur = 0;
    for (int tl = 0; tl < NT - 1; ++tl) {
        VMCNT(8); S_BARRIER();
        COMPUTE(cur);
        S_BARRIER();
        if (tl + 2 < NT) STAGE(cur, (tl + 2) * 64);
        cur ^= 1;
    }
    VMCNT(0); S_BARRIER();
    COMPUTE(cur);

#pragma unroll
    for (int i = 0; i < 4; ++i) {
#pragma unroll
        for (int ee = 0; ee < 4; ++ee) {
            int r = row0 + wr * 64 + i * 16 + q * 4 + ee;   // < M_ (174*128 exact)
            int b = r / NANCH, nl = r - b * NANCH;
#pragma unroll
            for (int j = 0; j < 4; ++j) {
                int o = wc * 64 + j * 16 + cl;
                Gt[((size_t)b * NO + o) * NANCHP + nl] = f2bf(acc[i][j][ee]);
            }
        }
    }
}

// ============ final (split-K x5, BK=32, R11 form): kc 0..3 = E·G1 (22 tiles), kc 4 = pf·W2^T (20) ============
__global__ __launch_bounds__(256, 4) void final_mfma_k(
    const ushort_t* __restrict__ E16,  // E [M_+32][2816] (unnormalized exp)
    const ushort_t* __restrict__ pf16, // [M_][640]
    const ushort_t* __restrict__ Gt,   // [B][128][2816]
    const ushort_t* __restrict__ W,    // hw16 [128][1280] (W2 = cols 640..1279)
    float* __restrict__ part)          // [5][M_][128] fp32 partials
{
    __shared__ __align__(16) ushort_t As[2][4096];
    __shared__ __align__(16) ushort_t Bs[2][4096];
    // grid 880: b=XCD (Gt[b] L2-resident), rb=row-slab 0..21, kc=chunk 0..4
    const int b = blockIdx.x & 7;
    const int u = blockIdx.x >> 3;
    const int rb = u % 22, kc = u / 22;
    // BK=32 tiles: E·G1 = tiles [0,88); pf·W2 = tiles [88,108)
    const int g0 = (kc < 4) ? kc * 22 : 88;
    const int NT = (kc < 4) ? 22 : 20;
    const int t = threadIdx.x;
    const int wid = t >> 6, lane = t & 63;
    const int wr = wid >> 1, wc = wid & 1;
    const int srow = lane >> 2;
    const int swk  = (((lane & 3) ^ ((lane >> 3) & 3)) * 8);
    // A rows may over-read past batch end (next batch / +32-row pad; pf16
    // over-read lands in aw16) -> row-independent garbage, discarded at write.
    const size_t arow = (size_t)b * NANCH + rb * 128 + wid * 32 + srow;
    const ushort_t* gAa = E16  + arow * NANCHP + swk;
    const ushort_t* gAp = pf16 + arow * D_ + swk;
    const ushort_t* gBg = Gt + ((size_t)b * NO + wid * 32 + srow) * NANCHP + swk;
    const ushort_t* gBw = W + (size_t)(wid * 32 + srow) * D2 + D_ + swk;
    f32x4 acc[4][4];
#pragma unroll
    for (int i = 0; i < 4; ++i)
#pragma unroll
        for (int j = 0; j < 4; ++j) acc[i][j] = (f32x4){0.f, 0.f, 0.f, 0.f};
    const int cl = lane & 15, q = lane >> 4;
    const int ra = wr * 64 + cl, rbb = wc * 64 + cl;
    const int aoff = ra * 32 + ((q ^ ((ra >> 1) & 3)) * 8);
    const int boff = rbb * 32 + ((q ^ ((rbb >> 1) & 3)) * 8);

    auto STAGE = [&](int buf, int gt) {     // gt = global K-tile index
        ushort_t* la = &As[buf][wid * 1024];
        ushort_t* lb = &Bs[buf][wid * 1024];
        if (gt < 88) {
            const int k0 = gt * 32;
            gload16(gAa + k0, la);
            gload16(gAa + k0 + (size_t)16 * NANCHP, la + 512);
            gload16(gBg + k0, lb);
            gload16(gBg + k0 + (size_t)16 * NANCHP, lb + 512);
        } else {
            const int kk = (gt - 88) * 32;
            gload16(gAp + kk, la);
            gload16(gAp + kk + (size_t)16 * D_, la + 512);
            gload16(gBw + kk, lb);
            gload16(gBw + kk + (size_t)16 * D2, lb + 512);
        }
    };
    auto COMPUTE = [&](int buf) {
        short8 af[4], bv[4];
#pragma unroll
        for (int i = 0; i < 4; ++i) af[i] = *(const short8*)&As[buf][aoff + i * 512];
#pragma unroll
        for (int j = 0; j < 4; ++j) bv[j] = *(const short8*)&Bs[buf][boff + j * 512];
        __builtin_amdgcn_s_setprio(1);
#pragma unroll
        for (int i = 0; i < 4; ++i)
#pragma unroll
            for (int j = 0; j < 4; ++j)
                acc[i][j] = __builtin_amdgcn_mfma_f32_16x16x32_bf16(af[i], bv[j], acc[i][j], 0, 0, 0);
        __builtin_amdgcn_s_setprio(0);
    };

    STAGE(0, g0); STAGE(1, g0 + 1);
    int cur = 0;
    for (int tl = 0; tl < NT - 1; ++tl) {
        VMCNT(4); S_BARRIER();
        COMPUTE(cur);
        S_BARRIER();
        if (tl + 2 < NT) STAGE(cur, g0 + tl + 2);
        cur ^= 1;
    }
    VMCNT(0); S_BARRIER();
    COMPUTE(cur);

    float* pout = part + (size_t)kc * M_ * NO;
#pragma unroll
    for (int i = 0; i < 4; ++i) {
#pragma unroll
        for (int ee = 0; ee < 4; ++ee) {
            int nl = rb * 128 + wr * 64 + i * 16 + q * 4 + ee;
            if (nl < NANCH) {
                int r = b * NANCH + nl;
#pragma unroll
                for (int j = 0; j < 4; ++j) {
                    int oo = wc * 64 + j * 16 + cl;
                    pout[(size_t)r * NO + oo] = acc[i][j][ee];
                }
            }
        }
    }
}

// ============ reduce: out = (p0+p1+p2+p3)/rsum + p4 + bias; heads epilogue ============
__global__ __launch_bounds__(256) void reduce_heads_k(
    const float* __restrict__ part,    // [5][M_][128]
    const float* __restrict__ rsum,
    const float* __restrict__ cls_b, const float* __restrict__ reg_b,
    const float* __restrict__ anchors,
    float* __restrict__ cls_out, float* __restrict__ lanes)
{
    int t = blockIdx.x * 256 + threadIdx.x;
    if (t >= M_ * 80) return;
    int r = t / 80, oo = t - r * 80;
    int nl = r % NANCH;
    if (oo < 75) {
        float inv = 1.0f / rsum[r];
        size_t base = (size_t)r * NO + oo, st = (size_t)M_ * NO;
        float v = ((part[base] + part[base + st]) + (part[base + 2 * st] + part[base + 3 * st])) * inv
                + part[base + 4 * st];
        if (oo < 2) {
            cls_out[(size_t)r * 2 + oo] = v + cls_b[oo];
        } else {
            int qq = oo - 2;
            int c = 4 + qq;
            float res = v + reg_b[qq];
            if (qq > 0) res += anchors[(size_t)nl * ALEN + c];
            lanes[(size_t)r * ALEN + c] = res;
        }
    } else if (oo < 79) {
        int c = oo - 75;                      // lanes cols 0..3 = anchors
        lanes[(size_t)r * ALEN + c] = anchors[(size_t)nl * ALEN + c];
    }
}

extern "C" void kernel_launch(void* const* d_in, const int* in_sizes, int n_in,
                              void* d_out, int out_size, void* d_ws, size_t ws_size,
                              hipStream_t stream)
{
    (void)in_sizes; (void)n_in; (void)out_size; (void)ws_size;
    const float* x       = (const float*)d_in[0];
    const float* conv_w  = (const float*)d_in[1];
    const float* conv_b  = (const float*)d_in[2];
    const float* attn_w  = (const float*)d_in[3];
    const float* attn_b  = (const float*)d_in[4];
    const float* cls_w   = (const float*)d_in[5];
    const float* cls_b   = (const float*)d_in[6];
    const float* reg_w   = (const float*)d_in[7];
    const float* reg_b   = (const float*)d_in[8];
    const float* anchors = (const float*)d_in[9];
    const int*   cut_xs  = (const int*)d_in[10];
    const unsigned char* invalid = (const unsigned char*)d_in[11];

    float* out     = (float*)d_out;
    float* cls_out = out;
    float* lanes   = out + (size_t)M_ * 2;
    float* attn    = out + (size_t)M_ * 2 + (size_t)M_ * ALEN;

    // workspace layout (~222 MB)
    char* w = (char*)d_ws;
    float* feat      = (float*)w;    w += (size_t)B_ * CF * HFM * WFM * 4;       // 512 KB
    ushort_t* pf16   = (ushort_t*)w; w += (size_t)M_ * D_ * 2;                   // 28.5 MB
    ushort_t* aw16   = (ushort_t*)w; w += (size_t)NMPAD * D_ * 2;                // 3.6 MB (absorbs pf16 over-read)
    ushort_t* hw16   = (ushort_t*)w; w += (size_t)128 * D2 * 2;                  // 320 KB
    ushort_t* Gt     = (ushort_t*)w; w += (size_t)B_ * NO * NANCHP * 2;          // 5.8 MB
    float* part      = (float*)w;    w += (size_t)5 * M_ * NO * 4;               // 57 MB
    float* rsum      = (float*)w;    w += (size_t)M_ * 4;                        // 89 KB
    ushort_t* E16    = (ushort_t*)w; w += (size_t)(M_ + 32) * NANCHP * 2;        // 125.6 MB

    conv_feat_k<<<(B_ * CF * HFM * WFM + 255) / 256, 256, 0, stream>>>(x, conv_w, conv_b, feat);
    gather_pf_k<<<(int)(((long long)M_ * D_ + 255) / 256), 256, 0, stream>>>(feat, cut_xs, invalid, pf16);
    prep_attn_w_k<<<(NMPAD * D_ + 255) / 256, 256, 0, stream>>>(attn_w, aw16);
    prep_heads_w_k<<<(128 * D2 + 255) / 256, 256, 0, stream>>>(cls_w, reg_w, hw16);

    gx_mfma_k<<<M_ / 128, 256, 0, stream>>>(pf16, hw16, Gt);
    zero_gtpad_k<<<(B_ * NO * 32 + 255) / 256, 256, 0, stream>>>(Gt);
    zero_epad_k<<<(M_ * 17 + 255) / 256, 256, 0, stream>>>(E16);

    scores_mfma_k<<<dim3(174 * 22), 256, 0, stream>>>(pf16, aw16, attn_b, E16);
    normalize_k<<<M_, 256, 0, stream>>>(E16, attn, rsum);

    final_mfma_k<<<dim3(5 * 22 * B_), 256, 0, stream>>>(E16, pf16, Gt, hw16, part);
    reduce_heads_k<<<(M_ * 80 + 255) / 256, 256, 0, stream>>>(part, rsum, cls_b, reg_b,
                                                              anchors, cls_out, lanes);
}

// Round 14
// 413.874 us; speedup vs baseline: 1.6330x; 1.1537x over previous
//
#include <hip/hip_runtime.h>

typedef unsigned short ushort_t;
typedef unsigned int   uint32;
typedef __attribute__((ext_vector_type(8))) short short8;   // 8 bf16 (4 VGPRs)
typedef __attribute__((ext_vector_type(4))) float f32x4;    // MFMA acc
typedef __attribute__((ext_vector_type(4))) uint32 u32x4;

// ---------------- problem constants ----------------
#define B_     8
#define CIN    512
#define HFM    10
#define WFM    25
#define CF     64
#define NANCH  2784          // N
#define NANCHP 2816          // N padded to 64 (K-tiling)
#define NM     2783          // N-1
#define NMPAD  2816          // N-1 padded (cols for scores)
#define D_     640           // CF*HFM
#define D2     1280
#define ALEN   77
#define M_     (B_*NANCH)    // 22272
#define NO     128           // padded head-output dim (75 used)

#define VMCNT(N)   asm volatile("s_waitcnt vmcnt(" #N ")" ::: "memory")
#define S_BARRIER() do { __builtin_amdgcn_s_barrier(); __builtin_amdgcn_sched_barrier(0); } while (0)

__device__ __forceinline__ ushort_t f2bf(float f) {
    uint32 u = __float_as_uint(f);
    u += 0x7fffu + ((u >> 16) & 1u);     // RNE
    return (ushort_t)(u >> 16);
}
__device__ __forceinline__ float bf2f(ushort_t h) {
    return __uint_as_float(((uint32)h) << 16);
}

__device__ __forceinline__ void gload16(const ushort_t* g, ushort_t* l) {
    __builtin_amdgcn_global_load_lds(
        (const __attribute__((address_space(1))) void*)g,
        (__attribute__((address_space(3))) void*)l, 16, 0, 0);
}

// ============ 1x1 conv ============
__global__ __launch_bounds__(256) void conv_feat_k(const float* __restrict__ x,
    const float* __restrict__ w, const float* __restrict__ bias,
    float* __restrict__ feat)
{
    int t = blockIdx.x * 256 + threadIdx.x;
    if (t >= B_ * CF * HFM * WFM) return;
    int pos = t % (HFM * WFM);
    int f   = (t / (HFM * WFM)) % CF;
    int b   = t / (CF * HFM * WFM);
    const float* xp = x + (size_t)b * CIN * HFM * WFM + pos;
    const float* wp = w + (size_t)f * CIN;
    float s = bias[f];
#pragma unroll 4
    for (int c = 0; c < CIN; ++c)
        s += xp[(size_t)c * (HFM * WFM)] * wp[c];
    feat[t] = s;
}

// ============ gather -> pf16 [M_][640] ============
__global__ __launch_bounds__(256) void gather_pf_k(const float* __restrict__ feat,
    const int* __restrict__ cut_xs, const unsigned char* __restrict__ invalid,
    ushort_t* __restrict__ pf16)
{
    long long t = (long long)blockIdx.x * 256 + threadIdx.x;
    if (t >= (long long)M_ * D_) return;
    int d = (int)(t % D_);
    int r = (int)(t / D_);
    int n = r % NANCH;
    int b = r / NANCH;
    int f = d / HFM, h = d - f * HFM;
    int idx = n * HFM + h;
    float v = 0.f;
    if (!invalid[idx]) {
        int xs = cut_xs[idx];
        v = feat[((size_t)(b * CF + f) * HFM + h) * WFM + xs];
    }
    pf16[t] = f2bf(v);
}

// ============ attn_w fp32 [2783][640] -> bf16 padded [2816][640] ============
__global__ __launch_bounds__(256) void prep_attn_w_k(const float* __restrict__ attn_w,
    ushort_t* __restrict__ w16)
{
    int t = blockIdx.x * 256 + threadIdx.x;
    if (t >= NMPAD * D_) return;
    int m = t / D_;
    w16[t] = (m < NM) ? f2bf(attn_w[(size_t)m * D_ + (t % D_)]) : (ushort_t)0;
}

// ============ heads weights -> bf16 padded [128][1280] ============
__global__ __launch_bounds__(256) void prep_heads_w_k(const float* __restrict__ cls_w,
    const float* __restrict__ reg_w, ushort_t* __restrict__ w16)
{
    int t = blockIdx.x * 256 + threadIdx.x;
    if (t >= 128 * D2) return;
    int o = t / D2, k = t % D2;
    float v = 0.f;
    if (o < 2)       v = cls_w[(size_t)o * D2 + k];
    else if (o < 75) v = reg_w[(size_t)(o - 2) * D2 + k];
    w16[t] = (o < 75) ? f2bf(v) : (ushort_t)0;
}

// ============ zero Gt K-pad cols [2784..2816) ============
__global__ __launch_bounds__(256) void zero_gtpad_k(ushort_t* __restrict__ Gt)
{
    int t = blockIdx.x * 256 + threadIdx.x;
    if (t >= B_ * NO * 32) return;
    int n = t & 31, o = (t >> 5) & (NO - 1), b = t >> 12;
    Gt[((size_t)b * NO + o) * NANCHP + NANCH + n] = 0;
}

// ============ zero E diag + K-pad cols (scores never writes these) ============
__global__ __launch_bounds__(256) void zero_epad_k(ushort_t* __restrict__ E)
{
    int t = blockIdx.x * 256 + threadIdx.x;
    if (t < M_) {
        E[(size_t)t * NANCHP + (t % NANCH)] = 0;            // diagonal
    } else if (t < M_ * 17) {
        int idx = t - M_;
        int r = idx >> 4, w = idx & 15;
        *(uint32*)&E[(size_t)r * NANCHP + NANCH + 2 * w] = 0;  // pad cols
    }
}

// --------------------------------------------------------------------------
// 128x128 / BK=32 / 4-wave (2x2) depth-2 counted-vmcnt template, 32KB LDS.
// __launch_bounds__(256,4): VGPR=64, zero spills, 4 blocks/CU. This is the
// validated optimum of the design family (R7-R13 bracket):
//   R10: (256,5) -> VGPR 48 -> acc spills (WRITE 793MB), 2.4x slower.
//   R12: no-LDS direct-load -> fragment regs spill (WRITE 224MB), 2.4x slower.
//   R13: wave-private LDS (no barriers) -> 2 blk/CU + 2x staging redundancy,
//        1.4x slower. Shared staging at max residency wins.
// Chunk-XOR swizzle (counter-verified 0 conflicts since R3).
// --------------------------------------------------------------------------

// ============ scores+exp MFMA: E[r][m+(m>=n)] = bf16(exp(pf·attn_w^T + attn_b)) ============
// exp without max-subtraction is safe: scores sigma ~= 0.06 (pf~0.23 x w~0.01 x K=640).
__global__ __launch_bounds__(256, 4) void scores_mfma_k(
    const ushort_t* __restrict__ A,   // pf16 [M_][640]
    const ushort_t* __restrict__ Bw,  // attnw16 [2816][640]
    const float* __restrict__ attn_b,
    ushort_t* __restrict__ E)         // E [M_+32][2816], unnormalized exp bf16
{
    __shared__ __align__(16) ushort_t As[2][4096];
    __shared__ __align__(16) ushort_t Bs[2][4096];
    // grid 3828 = 174 rowslabs x 22 colslabs; bijective XCD chunk (q=478,r=4)
    const int orig = blockIdx.x;
    const int xcd = orig & 7, pos = orig >> 3;
    const int start = (xcd < 4) ? xcd * 479 : 1916 + (xcd - 4) * 478;
    const int idx = start + pos;
    const int rowb = idx / 22, colb = idx - rowb * 22;
    const int row0 = rowb * 128, col0 = colb * 128;
    const int t = threadIdx.x;
    const int wid = t >> 6, lane = t & 63;
    const int wr = wid >> 1, wc = wid & 1;          // 2x2 wave grid, 64x64 each
    const int srow = lane >> 2;                      // 16 rows per gload
    const int swk  = (((lane & 3) ^ ((lane >> 3) & 3)) * 8);
    const ushort_t* gA = A  + (size_t)(row0 + wid * 32 + srow) * D_ + swk;
    const ushort_t* gB = Bw + (size_t)(col0 + wid * 32 + srow) * D_ + swk;
    f32x4 acc[4][4];
#pragma unroll
    for (int i = 0; i < 4; ++i)
#pragma unroll
        for (int j = 0; j < 4; ++j) acc[i][j] = (f32x4){0.f, 0.f, 0.f, 0.f};
    const int cl = lane & 15, q = lane >> 4;
    const int ra = wr * 64 + cl, rb = wc * 64 + cl;
    const int aoff = ra * 32 + ((q ^ ((ra >> 1) & 3)) * 8);
    const int boff = rb * 32 + ((q ^ ((rb >> 1) & 3)) * 8);

    auto STAGE = [&](int buf, int k0) {
        ushort_t* la = &As[buf][wid * 1024];
        ushort_t* lb = &Bs[buf][wid * 1024];
        gload16(gA + k0, la);
        gload16(gA + k0 + 16 * D_, la + 512);
        gload16(gB + k0, lb);
        gload16(gB + k0 + 16 * D_, lb + 512);
    };
    auto COMPUTE = [&](int buf) {
        short8 af[4], bv[4];
#pragma unroll
        for (int i = 0; i < 4; ++i) af[i] = *(const short8*)&As[buf][aoff + i * 512];
#pragma unroll
        for (int j = 0; j < 4; ++j) bv[j] = *(const short8*)&Bs[buf][boff + j * 512];
        __builtin_amdgcn_s_setprio(1);
#pragma unroll
        for (int i = 0; i < 4; ++i)
#pragma unroll
            for (int j = 0; j < 4; ++j)
                acc[i][j] = __builtin_amdgcn_mfma_f32_16x16x32_bf16(af[i], bv[j], acc[i][j], 0, 0, 0);
        __builtin_amdgcn_s_setprio(0);
    };

    const int NT = D_ / 32;                 // 20
    STAGE(0, 0); STAGE(1, 32);
    int cur = 0;
    for (int tl = 0; tl < NT - 1; ++tl) {
        VMCNT(4); S_BARRIER();              // tile tl landed; tl+1 (4 loads) in flight
        COMPUTE(cur);
        S_BARRIER();
        if (tl + 2 < NT) STAGE(cur, (tl + 2) * 32);
        cur ^= 1;
    }
    VMCNT(0); S_BARRIER();
    COMPUTE(cur);

#pragma unroll
    for (int i = 0; i < 4; ++i) {
#pragma unroll
        for (int ee = 0; ee < 4; ++ee) {
            int r = row0 + wr * 64 + i * 16 + q * 4 + ee;
            int n = r % NANCH;
            ushort_t* orow = E + (size_t)r * NANCHP;
#pragma unroll
            for (int j = 0; j < 4; ++j) {
                int m = col0 + wc * 64 + j * 16 + cl;
                if (m < NM) orow[m + (m >= n)] = f2bf(__expf(acc[i][j][ee] + attn_b[m]));
            }
        }
    }
}

// ============ normalize (vectorized, G13): attn[r][:] = E/sum (fp32); rsum[r] = sum ============
__global__ __launch_bounds__(256) void normalize_k(const ushort_t* __restrict__ E,
    float* __restrict__ attn, float* __restrict__ rsum)
{
    const int r = blockIdx.x;
    float* row = attn + (size_t)r * NANCH;
    const ushort_t* row16 = E + (size_t)r * NANCHP;
    const int t = threadIdx.x;
    __shared__ float red[4];
    float vals[16];                           // static-indexed -> VGPRs
    float s = 0.f;
#pragma unroll
    for (int i = 0; i < 2; ++i) {             // 348 short8-chunks per row (2784 = 348*8)
        int c = t + i * 256;
        float v0 = 0.f, v1 = 0.f, v2 = 0.f, v3 = 0.f, v4 = 0.f, v5 = 0.f, v6 = 0.f, v7 = 0.f;
        if (c < 348) {
            u32x4 u = *(const u32x4*)&row16[8 * c];   // 16B load: 8 bf16
            v0 = bf2f((ushort_t)(u.x & 0xffffu)); v1 = bf2f((ushort_t)(u.x >> 16));
            v2 = bf2f((ushort_t)(u.y & 0xffffu)); v3 = bf2f((ushort_t)(u.y >> 16));
            v4 = bf2f((ushort_t)(u.z & 0xffffu)); v5 = bf2f((ushort_t)(u.z >> 16));
            v6 = bf2f((ushort_t)(u.w & 0xffffu)); v7 = bf2f((ushort_t)(u.w >> 16));
        }
        vals[8 * i + 0] = v0; vals[8 * i + 1] = v1; vals[8 * i + 2] = v2; vals[8 * i + 3] = v3;
        vals[8 * i + 4] = v4; vals[8 * i + 5] = v5; vals[8 * i + 6] = v6; vals[8 * i + 7] = v7;
        s += ((v0 + v1) + (v2 + v3)) + ((v4 + v5) + (v6 + v7));
    }
    for (int off = 32; off; off >>= 1) s += __shfl_down(s, off);
    if ((t & 63) == 0) red[t >> 6] = s;
    __syncthreads();
    s = red[0] + red[1] + red[2] + red[3];
    float inv = 1.0f / s;
    if (t == 0) rsum[r] = s;
#pragma unroll
    for (int i = 0; i < 2; ++i) {
        int c = t + i * 256;
        if (c < 348) {
            float4 w0 = make_float4(vals[8 * i] * inv, vals[8 * i + 1] * inv,
                                    vals[8 * i + 2] * inv, vals[8 * i + 3] * inv);
            float4 w1 = make_float4(vals[8 * i + 4] * inv, vals[8 * i + 5] * inv,
                                    vals[8 * i + 6] * inv, vals[8 * i + 7] * inv);
            *(float4*)&row[8 * c]     = w0;   // 32B stores, 16B-aligned
            *(float4*)&row[8 * c + 4] = w1;
        }
    }
}

// ============ Gt[b][o][n] = (pf·W1^T)[n][o]  (W1 = hw16 cols 0..639) ============
__global__ __launch_bounds__(256, 2) void gx_mfma_k(
    const ushort_t* __restrict__ A,   // pf16 [M_][640]
    const ushort_t* __restrict__ W,   // hw16 [128][1280]
    ushort_t* __restrict__ Gt)        // [B][128][2816]
{
    __shared__ __align__(16) ushort_t As[2][8192];
    __shared__ __align__(16) ushort_t Bs[2][8192];
    const int t = threadIdx.x;
    const int wid = t >> 6, lane = t & 63;
    const int wr = wid >> 1, wc = wid & 1;          // 2x2 wave grid
    const int row0 = blockIdx.x * 128;
    const int r8 = lane >> 3;
    const int ck = (lane & 7) ^ r8;
    const ushort_t* gA = A + (size_t)(row0 + wid * 8 + r8) * D_ + ck * 8;
    const ushort_t* gB = W + (size_t)(wid * 8 + r8) * D2 + ck * 8;
    f32x4 acc[4][4];
#pragma unroll
    for (int i = 0; i < 4; ++i)
#pragma unroll
        for (int j = 0; j < 4; ++j) acc[i][j] = (f32x4){0.f, 0.f, 0.f, 0.f};
    const int cl = lane & 15, q = lane >> 4, cl7 = lane & 7;

    auto STAGE = [&](int buf, int k0) {
        ushort_t* la = &As[buf][wid * 512];
        ushort_t* lb = &Bs[buf][wid * 512];
#pragma unroll
        for (int j = 0; j < 4; ++j) {
            gload16(gA + k0 + (size_t)j * 32 * D_, la + j * 2048);
            gload16(gB + k0 + (size_t)j * 32 * D2, lb + j * 2048);
        }
    };
    auto COMPUTE = [&](int buf) {
#pragma unroll
        for (int ks = 0; ks < 2; ++ks) {
            short8 af[4], bv[4];
            const int co = ((ks * 4 + q) ^ cl7) * 8;
#pragma unroll
            for (int i = 0; i < 4; ++i)
                af[i] = *(const short8*)&As[buf][(wr * 64 + i * 16 + cl) * 64 + co];
#pragma unroll
            for (int j = 0; j < 4; ++j)
                bv[j] = *(const short8*)&Bs[buf][(wc * 64 + j * 16 + cl) * 64 + co];
            __builtin_amdgcn_s_setprio(1);
#pragma unroll
            for (int i = 0; i < 4; ++i)
#pragma unroll
                for (int j = 0; j < 4; ++j)
                    acc[i][j] = __builtin_amdgcn_mfma_f32_16x16x32_bf16(af[i], bv[j], acc[i][j], 0, 0, 0);
            __builtin_amdgcn_s_setprio(0);
        }
    };

    const int NT = D_ / 64;                 // 10
    STAGE(0, 0); STAGE(1, 64);
    int cur = 0;
    for (int tl = 0; tl < NT - 1; ++tl) {
        VMCNT(8); S_BARRIER();
        COMPUTE(cur);
        S_BARRIER();
        if (tl + 2 < NT) STAGE(cur, (tl + 2) * 64);
        cur ^= 1;
    }
    VMCNT(0); S_BARRIER();
    COMPUTE(cur);

#pragma unroll
    for (int i = 0; i < 4; ++i) {
#pragma unroll
        for (int ee = 0; ee < 4; ++ee) {
            int r = row0 + wr * 64 + i * 16 + q * 4 + ee;   // < M_ (174*128 exact)
            int b = r / NANCH, nl = r - b * NANCH;
#pragma unroll
            for (int j = 0; j < 4; ++j) {
                int o = wc * 64 + j * 16 + cl;
                Gt[((size_t)b * NO + o) * NANCHP + nl] = f2bf(acc[i][j][ee]);
            }
        }
    }
}

// ============ final (split-K x5, BK=32): kc 0..3 = E·G1 (22 tiles each), kc 4 = pf·W2^T (20) ============
__global__ __launch_bounds__(256, 4) void final_mfma_k(
    const ushort_t* __restrict__ E16,  // E [M_+32][2816] (unnormalized exp)
    const ushort_t* __restrict__ pf16, // [M_][640]
    const ushort_t* __restrict__ Gt,   // [B][128][2816]
    const ushort_t* __restrict__ W,    // hw16 [128][1280] (W2 = cols 640..1279)
    float* __restrict__ part)          // [5][M_][128] fp32 partials
{
    __shared__ __align__(16) ushort_t As[2][4096];
    __shared__ __align__(16) ushort_t Bs[2][4096];
    // grid 880: b=XCD (Gt[b] L2-resident), rb=row-slab 0..21, kc=chunk 0..4
    const int b = blockIdx.x & 7;
    const int u = blockIdx.x >> 3;
    const int rb = u % 22, kc = u / 22;
    // BK=32 tiles: E·G1 = tiles [0,88); pf·W2 = tiles [88,108)
    const int g0 = (kc < 4) ? kc * 22 : 88;
    const int NT = (kc < 4) ? 22 : 20;
    const int t = threadIdx.x;
    const int wid = t >> 6, lane = t & 63;
    const int wr = wid >> 1, wc = wid & 1;
    const int srow = lane >> 2;
    const int swk  = (((lane & 3) ^ ((lane >> 3) & 3)) * 8);
    // A rows may over-read past batch end (next batch / +32-row pad; pf16
    // over-read lands in aw16) -> row-independent garbage, discarded at write.
    const size_t arow = (size_t)b * NANCH + rb * 128 + wid * 32 + srow;
    const ushort_t* gAa = E16  + arow * NANCHP + swk;
    const ushort_t* gAp = pf16 + arow * D_ + swk;
    const ushort_t* gBg = Gt + ((size_t)b * NO + wid * 32 + srow) * NANCHP + swk;
    const ushort_t* gBw = W + (size_t)(wid * 32 + srow) * D2 + D_ + swk;
    f32x4 acc[4][4];
#pragma unroll
    for (int i = 0; i < 4; ++i)
#pragma unroll
        for (int j = 0; j < 4; ++j) acc[i][j] = (f32x4){0.f, 0.f, 0.f, 0.f};
    const int cl = lane & 15, q = lane >> 4;
    const int ra = wr * 64 + cl, rbb = wc * 64 + cl;
    const int aoff = ra * 32 + ((q ^ ((ra >> 1) & 3)) * 8);
    const int boff = rbb * 32 + ((q ^ ((rbb >> 1) & 3)) * 8);

    auto STAGE = [&](int buf, int gt) {     // gt = global K-tile index
        ushort_t* la = &As[buf][wid * 1024];
        ushort_t* lb = &Bs[buf][wid * 1024];
        if (gt < 88) {
            const int k0 = gt * 32;
            gload16(gAa + k0, la);
            gload16(gAa + k0 + (size_t)16 * NANCHP, la + 512);
            gload16(gBg + k0, lb);
            gload16(gBg + k0 + (size_t)16 * NANCHP, lb + 512);
        } else {
            const int kk = (gt - 88) * 32;
            gload16(gAp + kk, la);
            gload16(gAp + kk + (size_t)16 * D_, la + 512);
            gload16(gBw + kk, lb);
            gload16(gBw + kk + (size_t)16 * D2, lb + 512);
        }
    };
    auto COMPUTE = [&](int buf) {
        short8 af[4], bv[4];
#pragma unroll
        for (int i = 0; i < 4; ++i) af[i] = *(const short8*)&As[buf][aoff + i * 512];
#pragma unroll
        for (int j = 0; j < 4; ++j) bv[j] = *(const short8*)&Bs[buf][boff + j * 512];
        __builtin_amdgcn_s_setprio(1);
#pragma unroll
        for (int i = 0; i < 4; ++i)
#pragma unroll
            for (int j = 0; j < 4; ++j)
                acc[i][j] = __builtin_amdgcn_mfma_f32_16x16x32_bf16(af[i], bv[j], acc[i][j], 0, 0, 0);
        __builtin_amdgcn_s_setprio(0);
    };

    STAGE(0, g0); STAGE(1, g0 + 1);
    int cur = 0;
    for (int tl = 0; tl < NT - 1; ++tl) {
        VMCNT(4); S_BARRIER();
        COMPUTE(cur);
        S_BARRIER();
        if (tl + 2 < NT) STAGE(cur, g0 + tl + 2);
        cur ^= 1;
    }
    VMCNT(0); S_BARRIER();
    COMPUTE(cur);

    float* pout = part + (size_t)kc * M_ * NO;
#pragma unroll
    for (int i = 0; i < 4; ++i) {
#pragma unroll
        for (int ee = 0; ee < 4; ++ee) {
            int nl = rb * 128 + wr * 64 + i * 16 + q * 4 + ee;
            if (nl < NANCH) {
                int r = b * NANCH + nl;
#pragma unroll
                for (int j = 0; j < 4; ++j) {
                    int oo = wc * 64 + j * 16 + cl;
                    pout[(size_t)r * NO + oo] = acc[i][j][ee];
                }
            }
        }
    }
}

// ============ reduce: out = (p0+p1+p2+p3)/rsum + p4 + bias; heads epilogue ============
__global__ __launch_bounds__(256) void reduce_heads_k(
    const float* __restrict__ part,    // [5][M_][128]
    const float* __restrict__ rsum,
    const float* __restrict__ cls_b, const float* __restrict__ reg_b,
    const float* __restrict__ anchors,
    float* __restrict__ cls_out, float* __restrict__ lanes)
{
    int t = blockIdx.x * 256 + threadIdx.x;
    if (t >= M_ * 80) return;
    int r = t / 80, oo = t - r * 80;
    int nl = r % NANCH;
    if (oo < 75) {
        float inv = 1.0f / rsum[r];
        size_t base = (size_t)r * NO + oo, st = (size_t)M_ * NO;
        float v = ((part[base] + part[base + st]) + (part[base + 2 * st] + part[base + 3 * st])) * inv
                + part[base + 4 * st];
        if (oo < 2) {
            cls_out[(size_t)r * 2 + oo] = v + cls_b[oo];
        } else {
            int qq = oo - 2;
            int c = 4 + qq;
            float res = v + reg_b[qq];
            if (qq > 0) res += anchors[(size_t)nl * ALEN + c];
            lanes[(size_t)r * ALEN + c] = res;
        }
    } else if (oo < 79) {
        int c = oo - 75;                      // lanes cols 0..3 = anchors
        lanes[(size_t)r * ALEN + c] = anchors[(size_t)nl * ALEN + c];
    }
}

extern "C" void kernel_launch(void* const* d_in, const int* in_sizes, int n_in,
                              void* d_out, int out_size, void* d_ws, size_t ws_size,
                              hipStream_t stream)
{
    (void)in_sizes; (void)n_in; (void)out_size; (void)ws_size;
    const float* x       = (const float*)d_in[0];
    const float* conv_w  = (const float*)d_in[1];
    const float* conv_b  = (const float*)d_in[2];
    const float* attn_w  = (const float*)d_in[3];
    const float* attn_b  = (const float*)d_in[4];
    const float* cls_w   = (const float*)d_in[5];
    const float* cls_b   = (const float*)d_in[6];
    const float* reg_w   = (const float*)d_in[7];
    const float* reg_b   = (const float*)d_in[8];
    const float* anchors = (const float*)d_in[9];
    const int*   cut_xs  = (const int*)d_in[10];
    const unsigned char* invalid = (const unsigned char*)d_in[11];

    float* out     = (float*)d_out;
    float* cls_out = out;
    float* lanes   = out + (size_t)M_ * 2;
    float* attn    = out + (size_t)M_ * 2 + (size_t)M_ * ALEN;

    // workspace layout (~222 MB)
    char* w = (char*)d_ws;
    float* feat      = (float*)w;    w += (size_t)B_ * CF * HFM * WFM * 4;       // 512 KB
    ushort_t* pf16   = (ushort_t*)w; w += (size_t)M_ * D_ * 2;                   // 28.5 MB
    ushort_t* aw16   = (ushort_t*)w; w += (size_t)NMPAD * D_ * 2;                // 3.6 MB (absorbs pf16 over-read)
    ushort_t* hw16   = (ushort_t*)w; w += (size_t)128 * D2 * 2;                  // 320 KB
    ushort_t* Gt     = (ushort_t*)w; w += (size_t)B_ * NO * NANCHP * 2;          // 5.8 MB
    float* part      = (float*)w;    w += (size_t)5 * M_ * NO * 4;               // 57 MB
    float* rsum      = (float*)w;    w += (size_t)M_ * 4;                        // 89 KB
    ushort_t* E16    = (ushort_t*)w; w += (size_t)(M_ + 32) * NANCHP * 2;        // 125.6 MB

    conv_feat_k<<<(B_ * CF * HFM * WFM + 255) / 256, 256, 0, stream>>>(x, conv_w, conv_b, feat);
    gather_pf_k<<<(int)(((long long)M_ * D_ + 255) / 256), 256, 0, stream>>>(feat, cut_xs, invalid, pf16);
    prep_attn_w_k<<<(NMPAD * D_ + 255) / 256, 256, 0, stream>>>(attn_w, aw16);
    prep_heads_w_k<<<(128 * D2 + 255) / 256, 256, 0, stream>>>(cls_w, reg_w, hw16);

    gx_mfma_k<<<M_ / 128, 256, 0, stream>>>(pf16, hw16, Gt);
    zero_gtpad_k<<<(B_ * NO * 32 + 255) / 256, 256, 0, stream>>>(Gt);
    zero_epad_k<<<(M_ * 17 + 255) / 256, 256, 0, stream>>>(E16);

    scores_mfma_k<<<dim3(174 * 22), 256, 0, stream>>>(pf16, aw16, attn_b, E16);
    normalize_k<<<M_, 256, 0, stream>>>(E16, attn, rsum);

    final_mfma_k<<<dim3(5 * 22 * B_), 256, 0, stream>>>(E16, pf16, Gt, hw16, part);
    reduce_heads_k<<<(M_ * 80 + 255) / 256, 256, 0, stream>>>(part, rsum, cls_b, reg_b,
                                                              anchors, cls_out, lanes);
}

// Round 15
// 408.640 us; speedup vs baseline: 1.6539x; 1.0128x over previous
//
#include <hip/hip_runtime.h>

typedef unsigned short ushort_t;
typedef unsigned int   uint32;
typedef __attribute__((ext_vector_type(8))) short short8;   // 8 bf16 (4 VGPRs)
typedef __attribute__((ext_vector_type(4))) float f32x4;    // MFMA acc
typedef __attribute__((ext_vector_type(4))) uint32 u32x4;

// ---------------- problem constants ----------------
#define B_     8
#define CIN    512
#define HFM    10
#define WFM    25
#define CF     64
#define NANCH  2784          // N
#define NANCHP 2816          // N padded to 64 (K-tiling)
#define NM     2783          // N-1
#define NMPAD  2816          // N-1 padded (cols for scores)
#define D_     640           // CF*HFM
#define D2     1280
#define ALEN   77
#define M_     (B_*NANCH)    // 22272
#define NO     128           // padded head-output dim (75 used)

#define VMCNT(N)   asm volatile("s_waitcnt vmcnt(" #N ")" ::: "memory")
#define S_BARRIER() do { __builtin_amdgcn_s_barrier(); __builtin_amdgcn_sched_barrier(0); } while (0)

__device__ __forceinline__ ushort_t f2bf(float f) {
    uint32 u = __float_as_uint(f);
    u += 0x7fffu + ((u >> 16) & 1u);     // RNE
    return (ushort_t)(u >> 16);
}
__device__ __forceinline__ float bf2f(ushort_t h) {
    return __uint_as_float(((uint32)h) << 16);
}

__device__ __forceinline__ void gload16(const ushort_t* g, ushort_t* l) {
    __builtin_amdgcn_global_load_lds(
        (const __attribute__((address_space(1))) void*)g,
        (__attribute__((address_space(3))) void*)l, 16, 0, 0);
}

// ============ 1x1 conv ============
__global__ __launch_bounds__(256) void conv_feat_k(const float* __restrict__ x,
    const float* __restrict__ w, const float* __restrict__ bias,
    float* __restrict__ feat)
{
    int t = blockIdx.x * 256 + threadIdx.x;
    if (t >= B_ * CF * HFM * WFM) return;
    int pos = t % (HFM * WFM);
    int f   = (t / (HFM * WFM)) % CF;
    int b   = t / (CF * HFM * WFM);
    const float* xp = x + (size_t)b * CIN * HFM * WFM + pos;
    const float* wp = w + (size_t)f * CIN;
    float s = bias[f];
#pragma unroll 4
    for (int c = 0; c < CIN; ++c)
        s += xp[(size_t)c * (HFM * WFM)] * wp[c];
    feat[t] = s;
}

// ============ gather -> pf16 [M_][640] ============
__global__ __launch_bounds__(256) void gather_pf_k(const float* __restrict__ feat,
    const int* __restrict__ cut_xs, const unsigned char* __restrict__ invalid,
    ushort_t* __restrict__ pf16)
{
    long long t = (long long)blockIdx.x * 256 + threadIdx.x;
    if (t >= (long long)M_ * D_) return;
    int d = (int)(t % D_);
    int r = (int)(t / D_);
    int n = r % NANCH;
    int b = r / NANCH;
    int f = d / HFM, h = d - f * HFM;
    int idx = n * HFM + h;
    float v = 0.f;
    if (!invalid[idx]) {
        int xs = cut_xs[idx];
        v = feat[((size_t)(b * CF + f) * HFM + h) * WFM + xs];
    }
    pf16[t] = f2bf(v);
}

// ============ fused prep: attn_w->bf16 | heads_w->bf16 | Gt K-pad zero | E diag+pad zero ============
#define PREP_N1 (NMPAD * D_)          // 1,802,240  attn_w
#define PREP_N2 (128 * D2)            //   163,840  heads_w
#define PREP_N3 (B_ * NO * 32)        //    32,768  Gt pad
#define PREP_N4 (M_ * 17)             //   378,624  E diag (M_) + E pad (16*M_ u32)
#define PREP_TOT (PREP_N1 + PREP_N2 + PREP_N3 + PREP_N4)

__global__ __launch_bounds__(256) void prep_all_k(
    const float* __restrict__ attn_w, const float* __restrict__ cls_w,
    const float* __restrict__ reg_w,
    ushort_t* __restrict__ aw16, ushort_t* __restrict__ hw16,
    ushort_t* __restrict__ Gt, ushort_t* __restrict__ E)
{
    int t = blockIdx.x * 256 + threadIdx.x;
    if (t < PREP_N1) {
        int m = t / D_;
        aw16[t] = (m < NM) ? f2bf(attn_w[(size_t)m * D_ + (t % D_)]) : (ushort_t)0;
        return;
    }
    t -= PREP_N1;
    if (t < PREP_N2) {
        int o = t / D2, k = t % D2;
        float v = 0.f;
        if (o < 2)       v = cls_w[(size_t)o * D2 + k];
        else if (o < 75) v = reg_w[(size_t)(o - 2) * D2 + k];
        hw16[t] = (o < 75) ? f2bf(v) : (ushort_t)0;
        return;
    }
    t -= PREP_N2;
    if (t < PREP_N3) {
        int n = t & 31, o = (t >> 5) & (NO - 1), b = t >> 12;
        Gt[((size_t)b * NO + o) * NANCHP + NANCH + n] = 0;
        return;
    }
    t -= PREP_N3;
    if (t < M_) {
        E[(size_t)t * NANCHP + (t % NANCH)] = 0;            // diagonal
    } else {
        int idx = t - M_;
        int r = idx >> 4, w = idx & 15;
        *(uint32*)&E[(size_t)r * NANCHP + NANCH + 2 * w] = 0;  // pad cols
    }
}

// --------------------------------------------------------------------------
// 128x128 / BK=32 / 4-wave (2x2) depth-2 counted-vmcnt template, 32KB LDS.
// __launch_bounds__(256,4): VGPR=64, zero spills, 4 blocks/CU. Validated
// optimum of the design family (R7-R13 bracket):
//   R10: (256,5) -> VGPR 48 -> acc spills (WRITE 793MB), 2.4x slower.
//   R12: no-LDS direct-load -> fragment regs spill (WRITE 224MB), 2.4x slower.
//   R13: wave-private LDS (no barriers) -> 2 blk/CU + 2x staging redundancy,
//        1.4x slower. Shared staging at max residency wins.
//   R5:  256^2 2-phase -> 226us (1 blk/CU; 8-phase's ~1.3x over that = ~175,
//        still worse than this 154) -> 8-phase port has negative EV here.
// Chunk-XOR swizzle (counter-verified 0 conflicts since R3).
// --------------------------------------------------------------------------

// ============ scores+exp MFMA: E[r][m+(m>=n)] = bf16(exp(pf·attn_w^T + attn_b)) ============
// exp without max-subtraction is safe: scores sigma ~= 0.06 (pf~0.23 x w~0.01 x K=640).
__global__ __launch_bounds__(256, 4) void scores_mfma_k(
    const ushort_t* __restrict__ A,   // pf16 [M_][640]
    const ushort_t* __restrict__ Bw,  // attnw16 [2816][640]
    const float* __restrict__ attn_b,
    ushort_t* __restrict__ E)         // E [M_+32][2816], unnormalized exp bf16
{
    __shared__ __align__(16) ushort_t As[2][4096];
    __shared__ __align__(16) ushort_t Bs[2][4096];
    // grid 3828 = 174 rowslabs x 22 colslabs; bijective XCD chunk (q=478,r=4)
    const int orig = blockIdx.x;
    const int xcd = orig & 7, pos = orig >> 3;
    const int start = (xcd < 4) ? xcd * 479 : 1916 + (xcd - 4) * 478;
    const int idx = start + pos;
    const int rowb = idx / 22, colb = idx - rowb * 22;
    const int row0 = rowb * 128, col0 = colb * 128;
    const int t = threadIdx.x;
    const int wid = t >> 6, lane = t & 63;
    const int wr = wid >> 1, wc = wid & 1;          // 2x2 wave grid, 64x64 each
    const int srow = lane >> 2;                      // 16 rows per gload
    const int swk  = (((lane & 3) ^ ((lane >> 3) & 3)) * 8);
    const ushort_t* gA = A  + (size_t)(row0 + wid * 32 + srow) * D_ + swk;
    const ushort_t* gB = Bw + (size_t)(col0 + wid * 32 + srow) * D_ + swk;
    f32x4 acc[4][4];
#pragma unroll
    for (int i = 0; i < 4; ++i)
#pragma unroll
        for (int j = 0; j < 4; ++j) acc[i][j] = (f32x4){0.f, 0.f, 0.f, 0.f};
    const int cl = lane & 15, q = lane >> 4;
    const int ra = wr * 64 + cl, rb = wc * 64 + cl;
    const int aoff = ra * 32 + ((q ^ ((ra >> 1) & 3)) * 8);
    const int boff = rb * 32 + ((q ^ ((rb >> 1) & 3)) * 8);

    auto STAGE = [&](int buf, int k0) {
        ushort_t* la = &As[buf][wid * 1024];
        ushort_t* lb = &Bs[buf][wid * 1024];
        gload16(gA + k0, la);
        gload16(gA + k0 + 16 * D_, la + 512);
        gload16(gB + k0, lb);
        gload16(gB + k0 + 16 * D_, lb + 512);
    };
    auto COMPUTE = [&](int buf) {
        short8 af[4], bv[4];
#pragma unroll
        for (int i = 0; i < 4; ++i) af[i] = *(const short8*)&As[buf][aoff + i * 512];
#pragma unroll
        for (int j = 0; j < 4; ++j) bv[j] = *(const short8*)&Bs[buf][boff + j * 512];
        __builtin_amdgcn_s_setprio(1);
#pragma unroll
        for (int i = 0; i < 4; ++i)
#pragma unroll
            for (int j = 0; j < 4; ++j)
                acc[i][j] = __builtin_amdgcn_mfma_f32_16x16x32_bf16(af[i], bv[j], acc[i][j], 0, 0, 0);
        __builtin_amdgcn_s_setprio(0);
    };

    const int NT = D_ / 32;                 // 20
    STAGE(0, 0); STAGE(1, 32);
    int cur = 0;
    for (int tl = 0; tl < NT - 1; ++tl) {
        VMCNT(4); S_BARRIER();              // tile tl landed; tl+1 (4 loads) in flight
        COMPUTE(cur);
        S_BARRIER();
        if (tl + 2 < NT) STAGE(cur, (tl + 2) * 32);
        cur ^= 1;
    }
    VMCNT(0); S_BARRIER();
    COMPUTE(cur);

#pragma unroll
    for (int i = 0; i < 4; ++i) {
#pragma unroll
        for (int ee = 0; ee < 4; ++ee) {
            int r = row0 + wr * 64 + i * 16 + q * 4 + ee;
            int n = r % NANCH;
            ushort_t* orow = E + (size_t)r * NANCHP;
#pragma unroll
            for (int j = 0; j < 4; ++j) {
                int m = col0 + wc * 64 + j * 16 + cl;
                if (m < NM) orow[m + (m >= n)] = f2bf(__expf(acc[i][j][ee] + attn_b[m]));
            }
        }
    }
}

// ============ normalize (vectorized, G13): attn[r][:] = E/sum (fp32); rsum[r] = sum ============
__global__ __launch_bounds__(256) void normalize_k(const ushort_t* __restrict__ E,
    float* __restrict__ attn, float* __restrict__ rsum)
{
    const int r = blockIdx.x;
    float* row = attn + (size_t)r * NANCH;
    const ushort_t* row16 = E + (size_t)r * NANCHP;
    const int t = threadIdx.x;
    __shared__ float red[4];
    float vals[16];                           // static-indexed -> VGPRs
    float s = 0.f;
#pragma unroll
    for (int i = 0; i < 2; ++i) {             // 348 short8-chunks per row (2784 = 348*8)
        int c = t + i * 256;
        float v0 = 0.f, v1 = 0.f, v2 = 0.f, v3 = 0.f, v4 = 0.f, v5 = 0.f, v6 = 0.f, v7 = 0.f;
        if (c < 348) {
            u32x4 u = *(const u32x4*)&row16[8 * c];   // 16B load: 8 bf16
            v0 = bf2f((ushort_t)(u.x & 0xffffu)); v1 = bf2f((ushort_t)(u.x >> 16));
            v2 = bf2f((ushort_t)(u.y & 0xffffu)); v3 = bf2f((ushort_t)(u.y >> 16));
            v4 = bf2f((ushort_t)(u.z & 0xffffu)); v5 = bf2f((ushort_t)(u.z >> 16));
            v6 = bf2f((ushort_t)(u.w & 0xffffu)); v7 = bf2f((ushort_t)(u.w >> 16));
        }
        vals[8 * i + 0] = v0; vals[8 * i + 1] = v1; vals[8 * i + 2] = v2; vals[8 * i + 3] = v3;
        vals[8 * i + 4] = v4; vals[8 * i + 5] = v5; vals[8 * i + 6] = v6; vals[8 * i + 7] = v7;
        s += ((v0 + v1) + (v2 + v3)) + ((v4 + v5) + (v6 + v7));
    }
    for (int off = 32; off; off >>= 1) s += __shfl_down(s, off);
    if ((t & 63) == 0) red[t >> 6] = s;
    __syncthreads();
    s = red[0] + red[1] + red[2] + red[3];
    float inv = 1.0f / s;
    if (t == 0) rsum[r] = s;
#pragma unroll
    for (int i = 0; i < 2; ++i) {
        int c = t + i * 256;
        if (c < 348) {
            float4 w0 = make_float4(vals[8 * i] * inv, vals[8 * i + 1] * inv,
                                    vals[8 * i + 2] * inv, vals[8 * i + 3] * inv);
            float4 w1 = make_float4(vals[8 * i + 4] * inv, vals[8 * i + 5] * inv,
                                    vals[8 * i + 6] * inv, vals[8 * i + 7] * inv);
            *(float4*)&row[8 * c]     = w0;   // 32B stores, 16B-aligned
            *(float4*)&row[8 * c + 4] = w1;
        }
    }
}

// ============ Gt[b][o][n] = (pf·W1^T)[n][o]  (W1 = hw16 cols 0..639) ============
__global__ __launch_bounds__(256, 2) void gx_mfma_k(
    const ushort_t* __restrict__ A,   // pf16 [M_][640]
    const ushort_t* __restrict__ W,   // hw16 [128][1280]
    ushort_t* __restrict__ Gt)        // [B][128][2816]
{
    __shared__ __align__(16) ushort_t As[2][8192];
    __shared__ __align__(16) ushort_t Bs[2][8192];
    const int t = threadIdx.x;
    const int wid = t >> 6, lane = t & 63;
    const int wr = wid >> 1, wc = wid & 1;          // 2x2 wave grid
    const int row0 = blockIdx.x * 128;
    const int r8 = lane >> 3;
    const int ck = (lane & 7) ^ r8;
    const ushort_t* gA = A + (size_t)(row0 + wid * 8 + r8) * D_ + ck * 8;
    const ushort_t* gB = W + (size_t)(wid * 8 + r8) * D2 + ck * 8;
    f32x4 acc[4][4];
#pragma unroll
    for (int i = 0; i < 4; ++i)
#pragma unroll
        for (int j = 0; j < 4; ++j) acc[i][j] = (f32x4){0.f, 0.f, 0.f, 0.f};
    const int cl = lane & 15, q = lane >> 4, cl7 = lane & 7;

    auto STAGE = [&](int buf, int k0) {
        ushort_t* la = &As[buf][wid * 512];
        ushort_t* lb = &Bs[buf][wid * 512];
#pragma unroll
        for (int j = 0; j < 4; ++j) {
            gload16(gA + k0 + (size_t)j * 32 * D_, la + j * 2048);
            gload16(gB + k0 + (size_t)j * 32 * D2, lb + j * 2048);
        }
    };
    auto COMPUTE = [&](int buf) {
#pragma unroll
        for (int ks = 0; ks < 2; ++ks) {
            short8 af[4], bv[4];
            const int co = ((ks * 4 + q) ^ cl7) * 8;
#pragma unroll
            for (int i = 0; i < 4; ++i)
                af[i] = *(const short8*)&As[buf][(wr * 64 + i * 16 + cl) * 64 + co];
#pragma unroll
            for (int j = 0; j < 4; ++j)
                bv[j] = *(const short8*)&Bs[buf][(wc * 64 + j * 16 + cl) * 64 + co];
            __builtin_amdgcn_s_setprio(1);
#pragma unroll
            for (int i = 0; i < 4; ++i)
#pragma unroll
                for (int j = 0; j < 4; ++j)
                    acc[i][j] = __builtin_amdgcn_mfma_f32_16x16x32_bf16(af[i], bv[j], acc[i][j], 0, 0, 0);
            __builtin_amdgcn_s_setprio(0);
        }
    };

    const int NT = D_ / 64;                 // 10
    STAGE(0, 0); STAGE(1, 64);
    int cur = 0;
    for (int tl = 0; tl < NT - 1; ++tl) {
        VMCNT(8); S_BARRIER();
        COMPUTE(cur);
        S_BARRIER();
        if (tl + 2 < NT) STAGE(cur, (tl + 2) * 64);
        cur ^= 1;
    }
    VMCNT(0); S_BARRIER();
    COMPUTE(cur);

#pragma unroll
    for (int i = 0; i < 4; ++i) {
#pragma unroll
        for (int ee = 0; ee < 4; ++ee) {
            int r = row0 + wr * 64 + i * 16 + q * 4 + ee;   // < M_ (174*128 exact)
            int b = r / NANCH, nl = r - b * NANCH;
#pragma unroll
            for (int j = 0; j < 4; ++j) {
                int o = wc * 64 + j * 16 + cl;
                Gt[((size_t)b * NO + o) * NANCHP + nl] = f2bf(acc[i][j][ee]);
            }
        }
    }
}

// ============ final (split-K x5, BK=32): kc 0..3 = E·G1 (22 tiles each), kc 4 = pf·W2^T (20) ============
__global__ __launch_bounds__(256, 4) void final_mfma_k(
    const ushort_t* __restrict__ E16,  // E [M_+32][2816] (unnormalized exp)
    const ushort_t* __restrict__ pf16, // [M_][640]
    const ushort_t* __restrict__ Gt,   // [B][128][2816]
    const ushort_t* __restrict__ W,    // hw16 [128][1280] (W2 = cols 640..1279)
    float* __restrict__ part)          // [5][M_][128] fp32 partials
{
    __shared__ __align__(16) ushort_t As[2][4096];
    __shared__ __align__(16) ushort_t Bs[2][4096];
    // grid 880: b=XCD (Gt[b] L2-resident), rb=row-slab 0..21, kc=chunk 0..4
    const int b = blockIdx.x & 7;
    const int u = blockIdx.x >> 3;
    const int rb = u % 22, kc = u / 22;
    // BK=32 tiles: E·G1 = tiles [0,88); pf·W2 = tiles [88,108)
    const int g0 = (kc < 4) ? kc * 22 : 88;
    const int NT = (kc < 4) ? 22 : 20;
    const int t = threadIdx.x;
    const int wid = t >> 6, lane = t & 63;
    const int wr = wid >> 1, wc = wid & 1;
    const int srow = lane >> 2;
    const int swk  = (((lane & 3) ^ ((lane >> 3) & 3)) * 8);
    // A rows may over-read past batch end (next batch / +32-row pad; pf16
    // over-read lands in aw16) -> row-independent garbage, discarded at write.
    const size_t arow = (size_t)b * NANCH + rb * 128 + wid * 32 + srow;
    const ushort_t* gAa = E16  + arow * NANCHP + swk;
    const ushort_t* gAp = pf16 + arow * D_ + swk;
    const ushort_t* gBg = Gt + ((size_t)b * NO + wid * 32 + srow) * NANCHP + swk;
    const ushort_t* gBw = W + (size_t)(wid * 32 + srow) * D2 + D_ + swk;
    f32x4 acc[4][4];
#pragma unroll
    for (int i = 0; i < 4; ++i)
#pragma unroll
        for (int j = 0; j < 4; ++j) acc[i][j] = (f32x4){0.f, 0.f, 0.f, 0.f};
    const int cl = lane & 15, q = lane >> 4;
    const int ra = wr * 64 + cl, rbb = wc * 64 + cl;
    const int aoff = ra * 32 + ((q ^ ((ra >> 1) & 3)) * 8);
    const int boff = rbb * 32 + ((q ^ ((rbb >> 1) & 3)) * 8);

    auto STAGE = [&](int buf, int gt) {     // gt = global K-tile index
        ushort_t* la = &As[buf][wid * 1024];
        ushort_t* lb = &Bs[buf][wid * 1024];
        if (gt < 88) {
            const int k0 = gt * 32;
            gload16(gAa + k0, la);
            gload16(gAa + k0 + (size_t)16 * NANCHP, la + 512);
            gload16(gBg + k0, lb);
            gload16(gBg + k0 + (size_t)16 * NANCHP, lb + 512);
        } else {
            const int kk = (gt - 88) * 32;
            gload16(gAp + kk, la);
            gload16(gAp + kk + (size_t)16 * D_, la + 512);
            gload16(gBw + kk, lb);
            gload16(gBw + kk + (size_t)16 * D2, lb + 512);
        }
    };
    auto COMPUTE = [&](int buf) {
        short8 af[4], bv[4];
#pragma unroll
        for (int i = 0; i < 4; ++i) af[i] = *(const short8*)&As[buf][aoff + i * 512];
#pragma unroll
        for (int j = 0; j < 4; ++j) bv[j] = *(const short8*)&Bs[buf][boff + j * 512];
        __builtin_amdgcn_s_setprio(1);
#pragma unroll
        for (int i = 0; i < 4; ++i)
#pragma unroll
            for (int j = 0; j < 4; ++j)
                acc[i][j] = __builtin_amdgcn_mfma_f32_16x16x32_bf16(af[i], bv[j], acc[i][j], 0, 0, 0);
        __builtin_amdgcn_s_setprio(0);
    };

    STAGE(0, g0); STAGE(1, g0 + 1);
    int cur = 0;
    for (int tl = 0; tl < NT - 1; ++tl) {
        VMCNT(4); S_BARRIER();
        COMPUTE(cur);
        S_BARRIER();
        if (tl + 2 < NT) STAGE(cur, g0 + tl + 2);
        cur ^= 1;
    }
    VMCNT(0); S_BARRIER();
    COMPUTE(cur);

    float* pout = part + (size_t)kc * M_ * NO;
#pragma unroll
    for (int i = 0; i < 4; ++i) {
#pragma unroll
        for (int ee = 0; ee < 4; ++ee) {
            int nl = rb * 128 + wr * 64 + i * 16 + q * 4 + ee;
            if (nl < NANCH) {
                int r = b * NANCH + nl;
#pragma unroll
                for (int j = 0; j < 4; ++j) {
                    int oo = wc * 64 + j * 16 + cl;
                    pout[(size_t)r * NO + oo] = acc[i][j][ee];
                }
            }
        }
    }
}

// ============ reduce: out = (p0+p1+p2+p3)/rsum + p4 + bias; heads epilogue ============
__global__ __launch_bounds__(256) void reduce_heads_k(
    const float* __restrict__ part,    // [5][M_][128]
    const float* __restrict__ rsum,
    const float* __restrict__ cls_b, const float* __restrict__ reg_b,
    const float* __restrict__ anchors,
    float* __restrict__ cls_out, float* __restrict__ lanes)
{
    int t = blockIdx.x * 256 + threadIdx.x;
    if (t >= M_ * 80) return;
    int r = t / 80, oo = t - r * 80;
    int nl = r % NANCH;
    if (oo < 75) {
        float inv = 1.0f / rsum[r];
        size_t base = (size_t)r * NO + oo, st = (size_t)M_ * NO;
        float v = ((part[base] + part[base + st]) + (part[base + 2 * st] + part[base + 3 * st])) * inv
                + part[base + 4 * st];
        if (oo < 2) {
            cls_out[(size_t)r * 2 + oo] = v + cls_b[oo];
        } else {
            int qq = oo - 2;
            int c = 4 + qq;
            float res = v + reg_b[qq];
            if (qq > 0) res += anchors[(size_t)nl * ALEN + c];
            lanes[(size_t)r * ALEN + c] = res;
        }
    } else if (oo < 79) {
        int c = oo - 75;                      // lanes cols 0..3 = anchors
        lanes[(size_t)r * ALEN + c] = anchors[(size_t)nl * ALEN + c];
    }
}

extern "C" void kernel_launch(void* const* d_in, const int* in_sizes, int n_in,
                              void* d_out, int out_size, void* d_ws, size_t ws_size,
                              hipStream_t stream)
{
    (void)in_sizes; (void)n_in; (void)out_size; (void)ws_size;
    const float* x       = (const float*)d_in[0];
    const float* conv_w  = (const float*)d_in[1];
    const float* conv_b  = (const float*)d_in[2];
    const float* attn_w  = (const float*)d_in[3];
    const float* attn_b  = (const float*)d_in[4];
    const float* cls_w   = (const float*)d_in[5];
    const float* cls_b   = (const float*)d_in[6];
    const float* reg_w   = (const float*)d_in[7];
    const float* reg_b   = (const float*)d_in[8];
    const float* anchors = (const float*)d_in[9];
    const int*   cut_xs  = (const int*)d_in[10];
    const unsigned char* invalid = (const unsigned char*)d_in[11];

    float* out     = (float*)d_out;
    float* cls_out = out;
    float* lanes   = out + (size_t)M_ * 2;
    float* attn    = out + (size_t)M_ * 2 + (size_t)M_ * ALEN;

    // workspace layout (~222 MB)
    char* w = (char*)d_ws;
    float* feat      = (float*)w;    w += (size_t)B_ * CF * HFM * WFM * 4;       // 512 KB
    ushort_t* pf16   = (ushort_t*)w; w += (size_t)M_ * D_ * 2;                   // 28.5 MB
    ushort_t* aw16   = (ushort_t*)w; w += (size_t)NMPAD * D_ * 2;                // 3.6 MB (absorbs pf16 over-read)
    ushort_t* hw16   = (ushort_t*)w; w += (size_t)128 * D2 * 2;                  // 320 KB
    ushort_t* Gt     = (ushort_t*)w; w += (size_t)B_ * NO * NANCHP * 2;          // 5.8 MB
    float* part      = (float*)w;    w += (size_t)5 * M_ * NO * 4;               // 57 MB
    float* rsum      = (float*)w;    w += (size_t)M_ * 4;                        // 89 KB
    ushort_t* E16    = (ushort_t*)w; w += (size_t)(M_ + 32) * NANCHP * 2;        // 125.6 MB

    conv_feat_k<<<(B_ * CF * HFM * WFM + 255) / 256, 256, 0, stream>>>(x, conv_w, conv_b, feat);
    gather_pf_k<<<(int)(((long long)M_ * D_ + 255) / 256), 256, 0, stream>>>(feat, cut_xs, invalid, pf16);
    prep_all_k<<<(PREP_TOT + 255) / 256, 256, 0, stream>>>(attn_w, cls_w, reg_w,
                                                           aw16, hw16, Gt, E16);

    gx_mfma_k<<<M_ / 128, 256, 0, stream>>>(pf16, hw16, Gt);

    scores_mfma_k<<<dim3(174 * 22), 256, 0, stream>>>(pf16, aw16, attn_b, E16);
    normalize_k<<<M_, 256, 0, stream>>>(E16, attn, rsum);

    final_mfma_k<<<dim3(5 * 22 * B_), 256, 0, stream>>>(E16, pf16, Gt, hw16, part);
    reduce_heads_k<<<(M_ * 80 + 255) / 256, 256, 0, stream>>>(part, rsum, cls_b, reg_b,
                                                              anchors, cls_out, lanes);
}

// Round 16
// 374.804 us; speedup vs baseline: 1.8032x; 1.0903x over previous
//
#include <hip/hip_runtime.h>
#include <hip/hip_fp8.h>

typedef unsigned short ushort_t;
typedef unsigned char  uchar_t;
typedef unsigned int   uint32;
typedef __attribute__((ext_vector_type(8))) short short8;   // 8 bf16 (4 VGPRs)
typedef __attribute__((ext_vector_type(4))) float f32x4;    // MFMA acc
typedef __attribute__((ext_vector_type(4))) uint32 u32x4;
typedef long fp8x8;                                         // 8 fp8 (2 VGPRs)

// ---------------- problem constants ----------------
#define B_     8
#define CIN    512
#define HFM    10
#define WFM    25
#define CF     64
#define NANCH  2784          // N
#define NANCHP 2816          // N padded to 64 (K-tiling)
#define NM     2783          // N-1
#define NMPAD  2816          // N-1 padded (rows of attn_w buffer)
#define D_     640           // CF*HFM
#define D2     1280
#define ALEN   77
#define M_     (B_*NANCH)    // 22272
#define NO     128           // padded head-output dim (75 used)

#define VMCNT(N)   asm volatile("s_waitcnt vmcnt(" #N ")" ::: "memory")
#define S_BARRIER() do { __builtin_amdgcn_s_barrier(); __builtin_amdgcn_sched_barrier(0); } while (0)

__device__ __forceinline__ ushort_t f2bf(float f) {
    uint32 u = __float_as_uint(f);
    u += 0x7fffu + ((u >> 16) & 1u);     // RNE
    return (ushort_t)(u >> 16);
}
__device__ __forceinline__ float bf2f(ushort_t h) {
    return __uint_as_float(((uint32)h) << 16);
}
__device__ __forceinline__ uchar_t f2fp8(float f) {         // OCP e4m3fn
    __hip_fp8_e4m3 h(f);
    return (uchar_t)h.__x;
}

__device__ __forceinline__ void gload16(const ushort_t* g, ushort_t* l) {
    __builtin_amdgcn_global_load_lds(
        (const __attribute__((address_space(1))) void*)g,
        (__attribute__((address_space(3))) void*)l, 16, 0, 0);
}
__device__ __forceinline__ void gload16b(const uchar_t* g, uchar_t* l) {
    __builtin_amdgcn_global_load_lds(
        (const __attribute__((address_space(1))) void*)g,
        (__attribute__((address_space(3))) void*)l, 16, 0, 0);
}

// ============ 1x1 conv ============
__global__ __launch_bounds__(256) void conv_feat_k(const float* __restrict__ x,
    const float* __restrict__ w, const float* __restrict__ bias,
    float* __restrict__ feat)
{
    int t = blockIdx.x * 256 + threadIdx.x;
    if (t >= B_ * CF * HFM * WFM) return;
    int pos = t % (HFM * WFM);
    int f   = (t / (HFM * WFM)) % CF;
    int b   = t / (CF * HFM * WFM);
    const float* xp = x + (size_t)b * CIN * HFM * WFM + pos;
    const float* wp = w + (size_t)f * CIN;
    float s = bias[f];
#pragma unroll 4
    for (int c = 0; c < CIN; ++c)
        s += xp[(size_t)c * (HFM * WFM)] * wp[c];
    feat[t] = s;
}

// ============ gather -> pf16 [M_][640] bf16  +  pf8 [M_][640] fp8(v*4) ============
__global__ __launch_bounds__(256) void gather_pf_k(const float* __restrict__ feat,
    const int* __restrict__ cut_xs, const unsigned char* __restrict__ invalid,
    ushort_t* __restrict__ pf16, uchar_t* __restrict__ pf8)
{
    long long t = (long long)blockIdx.x * 256 + threadIdx.x;
    if (t >= (long long)M_ * D_) return;
    int d = (int)(t % D_);
    int r = (int)(t / D_);
    int n = r % NANCH;
    int b = r / NANCH;
    int f = d / HFM, h = d - f * HFM;
    int idx = n * HFM + h;
    float v = 0.f;
    if (!invalid[idx]) {
        int xs = cut_xs[idx];
        v = feat[((size_t)(b * CF + f) * HFM + h) * WFM + xs];
    }
    pf16[t] = f2bf(v);
    pf8[t]  = f2fp8(v * 4.f);           // scale sA=4 (compensated in scores epilogue)
}

// ============ fused prep: attn_w->fp8(w*32) | heads_w->bf16 | Gt K-pad zero | E diag+pad zero ============
#define PREP_N1 (NMPAD * D_)          // 1,802,240  attn_w -> aw8
#define PREP_N2 (128 * D2)            //   163,840  heads_w
#define PREP_N3 (B_ * NO * 32)        //    32,768  Gt pad
#define PREP_N4 (M_ * 17)             //   378,624  E diag (M_) + E pad (16*M_ u32)
#define PREP_TOT (PREP_N1 + PREP_N2 + PREP_N3 + PREP_N4)

__global__ __launch_bounds__(256) void prep_all_k(
    const float* __restrict__ attn_w, const float* __restrict__ cls_w,
    const float* __restrict__ reg_w,
    uchar_t* __restrict__ aw8, ushort_t* __restrict__ hw16,
    ushort_t* __restrict__ Gt, ushort_t* __restrict__ E)
{
    int t = blockIdx.x * 256 + threadIdx.x;
    if (t < PREP_N1) {
        int m = t / D_;
        aw8[t] = (m < NM) ? f2fp8(attn_w[(size_t)m * D_ + (t % D_)] * 32.f) : (uchar_t)0;
        return;                          // scale sB=32 (compensated in scores epilogue)
    }
    t -= PREP_N1;
    if (t < PREP_N2) {
        int o = t / D2, k = t % D2;
        float v = 0.f;
        if (o < 2)       v = cls_w[(size_t)o * D2 + k];
        else if (o < 75) v = reg_w[(size_t)(o - 2) * D2 + k];
        hw16[t] = (o < 75) ? f2bf(v) : (ushort_t)0;
        return;
    }
    t -= PREP_N2;
    if (t < PREP_N3) {
        int n = t & 31, o = (t >> 5) & (NO - 1), b = t >> 12;
        Gt[((size_t)b * NO + o) * NANCHP + NANCH + n] = 0;
        return;
    }
    t -= PREP_N3;
    if (t < M_) {
        E[(size_t)t * NANCHP + (t % NANCH)] = 0;            // diagonal
    } else {
        int idx = t - M_;
        int r = idx >> 4, w = idx & 15;
        *(uint32*)&E[(size_t)r * NANCHP + NANCH + 2 * w] = 0;  // pad cols
    }
}

// --------------------------------------------------------------------------
// scores: fp8 e4m3 / 128x128 / BK=64 / 4-wave / depth-2, 32KB LDS, 4 blk/CU.
// The R7-R11 law: time ~ iters x per-iter wall at fixed residency. bf16 BK=64
// needs 64KB -> 2 blk/CU (R8: slower). fp8 fits BK=64 in 32KB -> 10 iters
// (vs 20) at the SAME 4 blk/CU. MFMA fp8 = bf16 rate (m11) - not limiting.
// Operands pre-scaled (pf x4, w x32); epilogue multiplies by 1/128.
// Chunk-XOR swizzle on 16B units of each 64B K-window (same geometry as the
// validated bf16 layout): slot s of row R holds global unit s^((R>>1)&3);
// read frag (R, c=ks*4+q) at R*64 + ((c>>1)^((R>>1)&3))*16 + (c&1)*8
// -> 2 lanes/bank (free, m136). mfma_f32_16x16x32_fp8_fp8: lane(cl,q) holds
// k=q*8+e (8 bytes); C/D layout dtype-independent (m121/m127) -> epilogue same.
// --------------------------------------------------------------------------
__global__ __launch_bounds__(256, 4) void scores_mfma_k(
    const uchar_t* __restrict__ A8,   // pf8 [M_][640], values pf*4
    const uchar_t* __restrict__ B8,   // aw8 [2816][640], values w*32
    const float* __restrict__ attn_b,
    ushort_t* __restrict__ E)         // E [M_+32][2816], unnormalized exp bf16
{
    __shared__ __align__(16) uchar_t As[2][8192];
    __shared__ __align__(16) uchar_t Bs[2][8192];
    // grid 3828 = 174 rowslabs x 22 colslabs; bijective XCD chunk (q=478,r=4)
    const int orig = blockIdx.x;
    const int xcd = orig & 7, pos = orig >> 3;
    const int start = (xcd < 4) ? xcd * 479 : 1916 + (xcd - 4) * 478;
    const int idx = start + pos;
    const int rowb = idx / 22, colb = idx - rowb * 22;
    const int row0 = rowb * 128, col0 = colb * 128;
    const int t = threadIdx.x;
    const int wid = t >> 6, lane = t & 63;
    const int wr = wid >> 1, wc = wid & 1;          // 2x2 wave grid, 64x64 each
    const int srow = lane >> 2;                      // 16 rows per gload
    const int swku = (((lane & 3) ^ ((lane >> 3) & 3)) * 16);   // byte off of global unit
    const uchar_t* gA = A8 + (size_t)(row0 + wid * 32 + srow) * D_ + swku;
    const uchar_t* gB = B8 + (size_t)(col0 + wid * 32 + srow) * D_ + swku;
    f32x4 acc[4][4];
#pragma unroll
    for (int i = 0; i < 4; ++i)
#pragma unroll
        for (int j = 0; j < 4; ++j) acc[i][j] = (f32x4){0.f, 0.f, 0.f, 0.f};
    const int cl = lane & 15, q = lane >> 4;
    const int cv = (cl >> 1) & 3;

    auto STAGE = [&](int buf, int k0) {              // k0 in bytes (fp8 elems)
        uchar_t* la = &As[buf][wid * 2048];          // 32 rows x 64B per wave
        uchar_t* lb = &Bs[buf][wid * 2048];
        gload16b(gA + k0, la);
        gload16b(gA + k0 + 16 * D_, la + 1024);
        gload16b(gB + k0, lb);
        gload16b(gB + k0 + 16 * D_, lb + 1024);
    };
    auto COMPUTE = [&](int buf) {
#pragma unroll
        for (int ks = 0; ks < 2; ++ks) {             // K=64 tile = 2 x (K=32 MFMA)
            const int c = ks * 4 + q;
            const int co8 = (((c >> 1) ^ cv) * 16) + ((c & 1) * 8);
            fp8x8 af[4], bv[4];
#pragma unroll
            for (int i = 0; i < 4; ++i)
                af[i] = *(const fp8x8*)&As[buf][(wr * 64 + i * 16 + cl) * 64 + co8];
#pragma unroll
            for (int j = 0; j < 4; ++j)
                bv[j] = *(const fp8x8*)&Bs[buf][(wc * 64 + j * 16 + cl) * 64 + co8];
            __builtin_amdgcn_s_setprio(1);
#pragma unroll
            for (int i = 0; i < 4; ++i)
#pragma unroll
                for (int j = 0; j < 4; ++j)
                    acc[i][j] = __builtin_amdgcn_mfma_f32_16x16x32_fp8_fp8(af[i], bv[j], acc[i][j], 0, 0, 0);
            __builtin_amdgcn_s_setprio(0);
        }
    };

    const int NT = D_ / 64;                 // 10
    STAGE(0, 0); STAGE(1, 64);
    int cur = 0;
    for (int tl = 0; tl < NT - 1; ++tl) {
        VMCNT(4); S_BARRIER();              // tile tl landed; tl+1 (4 loads) in flight
        COMPUTE(cur);
        S_BARRIER();
        if (tl + 2 < NT) STAGE(cur, (tl + 2) * 64);
        cur ^= 1;
    }
    VMCNT(0); S_BARRIER();
    COMPUTE(cur);

    const float inv_sc = 1.0f / 128.0f;     // 1/(sA*sB)
#pragma unroll
    for (int i = 0; i < 4; ++i) {
#pragma unroll
        for (int ee = 0; ee < 4; ++ee) {
            int r = row0 + wr * 64 + i * 16 + q * 4 + ee;
            int n = r % NANCH;
            ushort_t* orow = E + (size_t)r * NANCHP;
#pragma unroll
            for (int j = 0; j < 4; ++j) {
                int m = col0 + wc * 64 + j * 16 + cl;
                if (m < NM) orow[m + (m >= n)] = f2bf(__expf(acc[i][j][ee] * inv_sc + attn_b[m]));
            }
        }
    }
}

// ============ normalize (vectorized, G13): attn[r][:] = E/sum (fp32); rsum[r] = sum ============
__global__ __launch_bounds__(256) void normalize_k(const ushort_t* __restrict__ E,
    float* __restrict__ attn, float* __restrict__ rsum)
{
    const int r = blockIdx.x;
    float* row = attn + (size_t)r * NANCH;
    const ushort_t* row16 = E + (size_t)r * NANCHP;
    const int t = threadIdx.x;
    __shared__ float red[4];
    float vals[16];                           // static-indexed -> VGPRs
    float s = 0.f;
#pragma unroll
    for (int i = 0; i < 2; ++i) {             // 348 short8-chunks per row (2784 = 348*8)
        int c = t + i * 256;
        float v0 = 0.f, v1 = 0.f, v2 = 0.f, v3 = 0.f, v4 = 0.f, v5 = 0.f, v6 = 0.f, v7 = 0.f;
        if (c < 348) {
            u32x4 u = *(const u32x4*)&row16[8 * c];   // 16B load: 8 bf16
            v0 = bf2f((ushort_t)(u.x & 0xffffu)); v1 = bf2f((ushort_t)(u.x >> 16));
            v2 = bf2f((ushort_t)(u.y & 0xffffu)); v3 = bf2f((ushort_t)(u.y >> 16));
            v4 = bf2f((ushort_t)(u.z & 0xffffu)); v5 = bf2f((ushort_t)(u.z >> 16));
            v6 = bf2f((ushort_t)(u.w & 0xffffu)); v7 = bf2f((ushort_t)(u.w >> 16));
        }
        vals[8 * i + 0] = v0; vals[8 * i + 1] = v1; vals[8 * i + 2] = v2; vals[8 * i + 3] = v3;
        vals[8 * i + 4] = v4; vals[8 * i + 5] = v5; vals[8 * i + 6] = v6; vals[8 * i + 7] = v7;
        s += ((v0 + v1) + (v2 + v3)) + ((v4 + v5) + (v6 + v7));
    }
    for (int off = 32; off; off >>= 1) s += __shfl_down(s, off);
    if ((t & 63) == 0) red[t >> 6] = s;
    __syncthreads();
    s = red[0] + red[1] + red[2] + red[3];
    float inv = 1.0f / s;
    if (t == 0) rsum[r] = s;
#pragma unroll
    for (int i = 0; i < 2; ++i) {
        int c = t + i * 256;
        if (c < 348) {
            float4 w0 = make_float4(vals[8 * i] * inv, vals[8 * i + 1] * inv,
                                    vals[8 * i + 2] * inv, vals[8 * i + 3] * inv);
            float4 w1 = make_float4(vals[8 * i + 4] * inv, vals[8 * i + 5] * inv,
                                    vals[8 * i + 6] * inv, vals[8 * i + 7] * inv);
            *(float4*)&row[8 * c]     = w0;   // 32B stores, 16B-aligned
            *(float4*)&row[8 * c + 4] = w1;
        }
    }
}

// ============ Gt[b][o][n] = (pf·W1^T)[n][o]  (W1 = hw16 cols 0..639) ============
__global__ __launch_bounds__(256, 2) void gx_mfma_k(
    const ushort_t* __restrict__ A,   // pf16 [M_][640]
    const ushort_t* __restrict__ W,   // hw16 [128][1280]
    ushort_t* __restrict__ Gt)        // [B][128][2816]
{
    __shared__ __align__(16) ushort_t As[2][8192];
    __shared__ __align__(16) ushort_t Bs[2][8192];
    const int t = threadIdx.x;
    const int wid = t >> 6, lane = t & 63;
    const int wr = wid >> 1, wc = wid & 1;          // 2x2 wave grid
    const int row0 = blockIdx.x * 128;
    const int r8 = lane >> 3;
    const int ck = (lane & 7) ^ r8;
    const ushort_t* gA = A + (size_t)(row0 + wid * 8 + r8) * D_ + ck * 8;
    const ushort_t* gB = W + (size_t)(wid * 8 + r8) * D2 + ck * 8;
    f32x4 acc[4][4];
#pragma unroll
    for (int i = 0; i < 4; ++i)
#pragma unroll
        for (int j = 0; j < 4; ++j) acc[i][j] = (f32x4){0.f, 0.f, 0.f, 0.f};
    const int cl = lane & 15, q = lane >> 4, cl7 = lane & 7;

    auto STAGE = [&](int buf, int k0) {
        ushort_t* la = &As[buf][wid * 512];
        ushort_t* lb = &Bs[buf][wid * 512];
#pragma unroll
        for (int j = 0; j < 4; ++j) {
            gload16(gA + k0 + (size_t)j * 32 * D_, la + j * 2048);
            gload16(gB + k0 + (size_t)j * 32 * D2, lb + j * 2048);
        }
    };
    auto COMPUTE = [&](int buf) {
#pragma unroll
        for (int ks = 0; ks < 2; ++ks) {
            short8 af[4], bv[4];
            const int co = ((ks * 4 + q) ^ cl7) * 8;
#pragma unroll
            for (int i = 0; i < 4; ++i)
                af[i] = *(const short8*)&As[buf][(wr * 64 + i * 16 + cl) * 64 + co];
#pragma unroll
            for (int j = 0; j < 4; ++j)
                bv[j] = *(const short8*)&Bs[buf][(wc * 64 + j * 16 + cl) * 64 + co];
            __builtin_amdgcn_s_setprio(1);
#pragma unroll
            for (int i = 0; i < 4; ++i)
#pragma unroll
                for (int j = 0; j < 4; ++j)
                    acc[i][j] = __builtin_amdgcn_mfma_f32_16x16x32_bf16(af[i], bv[j], acc[i][j], 0, 0, 0);
            __builtin_amdgcn_s_setprio(0);
        }
    };

    const int NT = D_ / 64;                 // 10
    STAGE(0, 0); STAGE(1, 64);
    int cur = 0;
    for (int tl = 0; tl < NT - 1; ++tl) {
        VMCNT(8); S_BARRIER();
        COMPUTE(cur);
        S_BARRIER();
        if (tl + 2 < NT) STAGE(cur, (tl + 2) * 64);
        cur ^= 1;
    }
    VMCNT(0); S_BARRIER();
    COMPUTE(cur);

#pragma unroll
    for (int i = 0; i < 4; ++i) {
#pragma unroll
        for (int ee = 0; ee < 4; ++ee) {
            int r = row0 + wr * 64 + i * 16 + q * 4 + ee;   // < M_ (174*128 exact)
            int b = r / NANCH, nl = r - b * NANCH;
#pragma unroll
            for (int j = 0; j < 4; ++j) {
                int o = wc * 64 + j * 16 + cl;
                Gt[((size_t)b * NO + o) * NANCHP + nl] = f2bf(acc[i][j][ee]);
            }
        }
    }
}

// ============ final (split-K x5, BK=32): kc 0..3 = E·G1 (22 tiles each), kc 4 = pf·W2^T (20) ============
__global__ __launch_bounds__(256, 4) void final_mfma_k(
    const ushort_t* __restrict__ E16,  // E [M_+32][2816] (unnormalized exp)
    const ushort_t* __restrict__ pf16, // [M_][640]
    const ushort_t* __restrict__ Gt,   // [B][128][2816]
    const ushort_t* __restrict__ W,    // hw16 [128][1280] (W2 = cols 640..1279)
    float* __restrict__ part)          // [5][M_][128] fp32 partials
{
    __shared__ __align__(16) ushort_t As[2][4096];
    __shared__ __align__(16) ushort_t Bs[2][4096];
    // grid 880: b=XCD (Gt[b] L2-resident), rb=row-slab 0..21, kc=chunk 0..4
    const int b = blockIdx.x & 7;
    const int u = blockIdx.x >> 3;
    const int rb = u % 22, kc = u / 22;
    // BK=32 tiles: E·G1 = tiles [0,88); pf·W2 = tiles [88,108)
    const int g0 = (kc < 4) ? kc * 22 : 88;
    const int NT = (kc < 4) ? 22 : 20;
    const int t = threadIdx.x;
    const int wid = t >> 6, lane = t & 63;
    const int wr = wid >> 1, wc = wid & 1;
    const int srow = lane >> 2;
    const int swk  = (((lane & 3) ^ ((lane >> 3) & 3)) * 8);
    // A rows may over-read past batch end (next batch / +32-row pad; pf16
    // over-read lands in pf8) -> row-independent garbage, discarded at write.
    const size_t arow = (size_t)b * NANCH + rb * 128 + wid * 32 + srow;
    const ushort_t* gAa = E16  + arow * NANCHP + swk;
    const ushort_t* gAp = pf16 + arow * D_ + swk;
    const ushort_t* gBg = Gt + ((size_t)b * NO + wid * 32 + srow) * NANCHP + swk;
    const ushort_t* gBw = W + (size_t)(wid * 32 + srow) * D2 + D_ + swk;
    f32x4 acc[4][4];
#pragma unroll
    for (int i = 0; i < 4; ++i)
#pragma unroll
        for (int j = 0; j < 4; ++j) acc[i][j] = (f32x4){0.f, 0.f, 0.f, 0.f};
    const int cl = lane & 15, q = lane >> 4;
    const int ra = wr * 64 + cl, rbb = wc * 64 + cl;
    const int aoff = ra * 32 + ((q ^ ((ra >> 1) & 3)) * 8);
    const int boff = rbb * 32 + ((q ^ ((rbb >> 1) & 3)) * 8);

    auto STAGE = [&](int buf, int gt) {     // gt = global K-tile index
        ushort_t* la = &As[buf][wid * 1024];
        ushort_t* lb = &Bs[buf][wid * 1024];
        if (gt < 88) {
            const int k0 = gt * 32;
            gload16(gAa + k0, la);
            gload16(gAa + k0 + (size_t)16 * NANCHP, la + 512);
            gload16(gBg + k0, lb);
            gload16(gBg + k0 + (size_t)16 * NANCHP, lb + 512);
        } else {
            const int kk = (gt - 88) * 32;
            gload16(gAp + kk, la);
            gload16(gAp + kk + (size_t)16 * D_, la + 512);
            gload16(gBw + kk, lb);
            gload16(gBw + kk + (size_t)16 * D2, lb + 512);
        }
    };
    auto COMPUTE = [&](int buf) {
        short8 af[4], bv[4];
#pragma unroll
        for (int i = 0; i < 4; ++i) af[i] = *(const short8*)&As[buf][aoff + i * 512];
#pragma unroll
        for (int j = 0; j < 4; ++j) bv[j] = *(const short8*)&Bs[buf][boff + j * 512];
        __builtin_amdgcn_s_setprio(1);
#pragma unroll
        for (int i = 0; i < 4; ++i)
#pragma unroll
            for (int j = 0; j < 4; ++j)
                acc[i][j] = __builtin_amdgcn_mfma_f32_16x16x32_bf16(af[i], bv[j], acc[i][j], 0, 0, 0);
        __builtin_amdgcn_s_setprio(0);
    };

    STAGE(0, g0); STAGE(1, g0 + 1);
    int cur = 0;
    for (int tl = 0; tl < NT - 1; ++tl) {
        VMCNT(4); S_BARRIER();
        COMPUTE(cur);
        S_BARRIER();
        if (tl + 2 < NT) STAGE(cur, g0 + tl + 2);
        cur ^= 1;
    }
    VMCNT(0); S_BARRIER();
    COMPUTE(cur);

    float* pout = part + (size_t)kc * M_ * NO;
#pragma unroll
    for (int i = 0; i < 4; ++i) {
#pragma unroll
        for (int ee = 0; ee < 4; ++ee) {
            int nl = rb * 128 + wr * 64 + i * 16 + q * 4 + ee;
            if (nl < NANCH) {
                int r = b * NANCH + nl;
#pragma unroll
                for (int j = 0; j < 4; ++j) {
                    int oo = wc * 64 + j * 16 + cl;
                    pout[(size_t)r * NO + oo] = acc[i][j][ee];
                }
            }
        }
    }
}

// ============ reduce: out = (p0+p1+p2+p3)/rsum + p4 + bias; heads epilogue ============
__global__ __launch_bounds__(256) void reduce_heads_k(
    const float* __restrict__ part,    // [5][M_][128]
    const float* __restrict__ rsum,
    const float* __restrict__ cls_b, const float* __restrict__ reg_b,
    const float* __restrict__ anchors,
    float* __restrict__ cls_out, float* __restrict__ lanes)
{
    int t = blockIdx.x * 256 + threadIdx.x;
    if (t >= M_ * 80) return;
    int r = t / 80, oo = t - r * 80;
    int nl = r % NANCH;
    if (oo < 75) {
        float inv = 1.0f / rsum[r];
        size_t base = (size_t)r * NO + oo, st = (size_t)M_ * NO;
        float v = ((part[base] + part[base + st]) + (part[base + 2 * st] + part[base + 3 * st])) * inv
                + part[base + 4 * st];
        if (oo < 2) {
            cls_out[(size_t)r * 2 + oo] = v + cls_b[oo];
        } else {
            int qq = oo - 2;
            int c = 4 + qq;
            float res = v + reg_b[qq];
            if (qq > 0) res += anchors[(size_t)nl * ALEN + c];
            lanes[(size_t)r * ALEN + c] = res;
        }
    } else if (oo < 79) {
        int c = oo - 75;                      // lanes cols 0..3 = anchors
        lanes[(size_t)r * ALEN + c] = anchors[(size_t)nl * ALEN + c];
    }
}

extern "C" void kernel_launch(void* const* d_in, const int* in_sizes, int n_in,
                              void* d_out, int out_size, void* d_ws, size_t ws_size,
                              hipStream_t stream)
{
    (void)in_sizes; (void)n_in; (void)out_size; (void)ws_size;
    const float* x       = (const float*)d_in[0];
    const float* conv_w  = (const float*)d_in[1];
    const float* conv_b  = (const float*)d_in[2];
    const float* attn_w  = (const float*)d_in[3];
    const float* attn_b  = (const float*)d_in[4];
    const float* cls_w   = (const float*)d_in[5];
    const float* cls_b   = (const float*)d_in[6];
    const float* reg_w   = (const float*)d_in[7];
    const float* reg_b   = (const float*)d_in[8];
    const float* anchors = (const float*)d_in[9];
    const int*   cut_xs  = (const int*)d_in[10];
    const unsigned char* invalid = (const unsigned char*)d_in[11];

    float* out     = (float*)d_out;
    float* cls_out = out;
    float* lanes   = out + (size_t)M_ * 2;
    float* attn    = out + (size_t)M_ * 2 + (size_t)M_ * ALEN;

    // workspace layout (~235 MB)
    char* w = (char*)d_ws;
    float* feat      = (float*)w;    w += (size_t)B_ * CF * HFM * WFM * 4;       // 512 KB
    ushort_t* pf16   = (ushort_t*)w; w += (size_t)M_ * D_ * 2;                   // 28.5 MB
    uchar_t* pf8     = (uchar_t*)w;  w += (size_t)M_ * D_;                       // 14.3 MB (absorbs pf16 over-read)
    uchar_t* aw8     = (uchar_t*)w;  w += (size_t)NMPAD * D_;                    // 1.8 MB
    ushort_t* hw16   = (ushort_t*)w; w += (size_t)128 * D2 * 2;                  // 320 KB
    ushort_t* Gt     = (ushort_t*)w; w += (size_t)B_ * NO * NANCHP * 2;          // 5.8 MB
    float* part      = (float*)w;    w += (size_t)5 * M_ * NO * 4;               // 57 MB
    float* rsum      = (float*)w;    w += (size_t)M_ * 4;                        // 89 KB
    ushort_t* E16    = (ushort_t*)w; w += (size_t)(M_ + 32) * NANCHP * 2;        // 125.6 MB

    conv_feat_k<<<(B_ * CF * HFM * WFM + 255) / 256, 256, 0, stream>>>(x, conv_w, conv_b, feat);
    gather_pf_k<<<(int)(((long long)M_ * D_ + 255) / 256), 256, 0, stream>>>(feat, cut_xs, invalid, pf16, pf8);
    prep_all_k<<<(PREP_TOT + 255) / 256, 256, 0, stream>>>(attn_w, cls_w, reg_w,
                                                           aw8, hw16, Gt, E16);

    gx_mfma_k<<<M_ / 128, 256, 0, stream>>>(pf16, hw16, Gt);

    scores_mfma_k<<<dim3(174 * 22), 256, 0, stream>>>(pf8, aw8, attn_b, E16);
    normalize_k<<<M_, 256, 0, stream>>>(E16, attn, rsum);

    final_mfma_k<<<dim3(5 * 22 * B_), 256, 0, stream>>>(E16, pf16, Gt, hw16, part);
    reduce_heads_k<<<(M_ * 80 + 255) / 256, 256, 0, stream>>>(part, rsum, cls_b, reg_b,
                                                              anchors, cls_out, lanes);
}

// Round 17
// 358.818 us; speedup vs baseline: 1.8836x; 1.0446x over previous
//
#include <hip/hip_runtime.h>
#include <hip/hip_fp8.h>

typedef unsigned short ushort_t;
typedef unsigned char  uchar_t;
typedef unsigned int   uint32;
typedef __attribute__((ext_vector_type(8))) short short8;   // 8 bf16 (4 VGPRs)
typedef __attribute__((ext_vector_type(4))) float f32x4;    // MFMA acc
typedef __attribute__((ext_vector_type(4))) uint32 u32x4;
typedef long fp8x8;                                         // 8 fp8 (2 VGPRs)

// ---------------- problem constants ----------------
#define B_     8
#define CIN    512
#define HFM    10
#define WFM    25
#define CF     64
#define NANCH  2784          // N
#define NANCHP 2816          // N padded to 64 (K-tiling)
#define NM     2783          // N-1
#define NMPAD  2816          // N-1 padded (rows of attn_w buffer)
#define D_     640           // CF*HFM
#define D2     1280
#define ALEN   77
#define M_     (B_*NANCH)    // 22272
#define NO     128           // padded head-output dim (75 used)

#define VMCNT(N)   asm volatile("s_waitcnt vmcnt(" #N ")" ::: "memory")
#define S_BARRIER() do { __builtin_amdgcn_s_barrier(); __builtin_amdgcn_sched_barrier(0); } while (0)

__device__ __forceinline__ ushort_t f2bf(float f) {
    uint32 u = __float_as_uint(f);
    u += 0x7fffu + ((u >> 16) & 1u);     // RNE
    return (ushort_t)(u >> 16);
}
__device__ __forceinline__ float bf2f(ushort_t h) {
    return __uint_as_float(((uint32)h) << 16);
}
__device__ __forceinline__ uchar_t f2fp8(float f) {         // OCP e4m3fn
    __hip_fp8_e4m3 h(f);
    return (uchar_t)h.__x;
}
__device__ __forceinline__ float fp82f(uint32 b) {
    __hip_fp8_e4m3 h; h.__x = (uchar_t)b; return (float)h;
}

__device__ __forceinline__ void gload16(const ushort_t* g, ushort_t* l) {
    __builtin_amdgcn_global_load_lds(
        (const __attribute__((address_space(1))) void*)g,
        (__attribute__((address_space(3))) void*)l, 16, 0, 0);
}
__device__ __forceinline__ void gload16b(const uchar_t* g, uchar_t* l) {
    __builtin_amdgcn_global_load_lds(
        (const __attribute__((address_space(1))) void*)g,
        (__attribute__((address_space(3))) void*)l, 16, 0, 0);
}

// ============ 1x1 conv ============
__global__ __launch_bounds__(256) void conv_feat_k(const float* __restrict__ x,
    const float* __restrict__ w, const float* __restrict__ bias,
    float* __restrict__ feat)
{
    int t = blockIdx.x * 256 + threadIdx.x;
    if (t >= B_ * CF * HFM * WFM) return;
    int pos = t % (HFM * WFM);
    int f   = (t / (HFM * WFM)) % CF;
    int b   = t / (CF * HFM * WFM);
    const float* xp = x + (size_t)b * CIN * HFM * WFM + pos;
    const float* wp = w + (size_t)f * CIN;
    float s = bias[f];
#pragma unroll 4
    for (int c = 0; c < CIN; ++c)
        s += xp[(size_t)c * (HFM * WFM)] * wp[c];
    feat[t] = s;
}

// ============ gather -> pf16 [M_][640] bf16  +  pf8 [M_][640] fp8(v*4) ============
__global__ __launch_bounds__(256) void gather_pf_k(const float* __restrict__ feat,
    const int* __restrict__ cut_xs, const unsigned char* __restrict__ invalid,
    ushort_t* __restrict__ pf16, uchar_t* __restrict__ pf8)
{
    long long t = (long long)blockIdx.x * 256 + threadIdx.x;
    if (t >= (long long)M_ * D_) return;
    int d = (int)(t % D_);
    int r = (int)(t / D_);
    int n = r % NANCH;
    int b = r / NANCH;
    int f = d / HFM, h = d - f * HFM;
    int idx = n * HFM + h;
    float v = 0.f;
    if (!invalid[idx]) {
        int xs = cut_xs[idx];
        v = feat[((size_t)(b * CF + f) * HFM + h) * WFM + xs];
    }
    pf16[t] = f2bf(v);
    pf8[t]  = f2fp8(v * 4.f);           // scale sA=4 (compensated in scores epilogue)
}

// ============ fused prep: attn_w->fp8(w*32) | heads_w->bf16 | G8 K-pad zero | E8 diag+pad zero ============
#define PREP_N1 (NMPAD * D_)          // 1,802,240  attn_w -> aw8
#define PREP_N2 (128 * D2)            //   163,840  heads_w
#define PREP_N3 (B_ * NO * 32)        //    32,768  G8 pad (1B each)
#define PREP_N4 (M_ * 9)              //   200,448  E8 diag (M_) + E8 pad (8*M_ u32)
#define PREP_TOT (PREP_N1 + PREP_N2 + PREP_N3 + PREP_N4)

__global__ __launch_bounds__(256) void prep_all_k(
    const float* __restrict__ attn_w, const float* __restrict__ cls_w,
    const float* __restrict__ reg_w,
    uchar_t* __restrict__ aw8, ushort_t* __restrict__ hw16,
    uchar_t* __restrict__ G8, uchar_t* __restrict__ E8)
{
    int t = blockIdx.x * 256 + threadIdx.x;
    if (t < PREP_N1) {
        int m = t / D_;
        aw8[t] = (m < NM) ? f2fp8(attn_w[(size_t)m * D_ + (t % D_)] * 32.f) : (uchar_t)0;
        return;                          // scale sB=32 (compensated in scores epilogue)
    }
    t -= PREP_N1;
    if (t < PREP_N2) {
        int o = t / D2, k = t % D2;
        float v = 0.f;
        if (o < 2)       v = cls_w[(size_t)o * D2 + k];
        else if (o < 75) v = reg_w[(size_t)(o - 2) * D2 + k];
        hw16[t] = (o < 75) ? f2bf(v) : (ushort_t)0;
        return;
    }
    t -= PREP_N2;
    if (t < PREP_N3) {
        int n = t & 31, o = (t >> 5) & (NO - 1), b = t >> 12;
        G8[((size_t)b * NO + o) * NANCHP + NANCH + n] = 0;
        return;
    }
    t -= PREP_N3;
    if (t < M_) {
        E8[(size_t)t * NANCHP + (t % NANCH)] = 0;            // diagonal
    } else {
        int idx = t - M_;
        int r = idx >> 3, w = idx & 7;
        *(uint32*)&E8[(size_t)r * NANCHP + NANCH + 4 * w] = 0;  // pad cols (32B/row)
    }
}

// --------------------------------------------------------------------------
// scores: fp8 e4m3 / 128x128 / BK=64 / 4-wave / depth-2, 32KB LDS, 4 blk/CU
// (R16-validated: iters halved at constant residency -> time halved).
// E now stored fp8 (x16 scale): scale cancels in attn=E8/sum(E8) and is
// compensated in reduce (1/(64*rsum)); halves E write+read traffic.
// --------------------------------------------------------------------------
__global__ __launch_bounds__(256, 4) void scores_mfma_k(
    const uchar_t* __restrict__ A8,   // pf8 [M_][640], values pf*4
    const uchar_t* __restrict__ B8,   // aw8 [2816][640], values w*32
    const float* __restrict__ attn_b,
    uchar_t* __restrict__ E8)         // E8 [M_+32][2816], fp8(exp*16)
{
    __shared__ __align__(16) uchar_t As[2][8192];
    __shared__ __align__(16) uchar_t Bs[2][8192];
    // grid 3828 = 174 rowslabs x 22 colslabs; bijective XCD chunk (q=478,r=4)
    const int orig = blockIdx.x;
    const int xcd = orig & 7, pos = orig >> 3;
    const int start = (xcd < 4) ? xcd * 479 : 1916 + (xcd - 4) * 478;
    const int idx = start + pos;
    const int rowb = idx / 22, colb = idx - rowb * 22;
    const int row0 = rowb * 128, col0 = colb * 128;
    const int t = threadIdx.x;
    const int wid = t >> 6, lane = t & 63;
    const int wr = wid >> 1, wc = wid & 1;          // 2x2 wave grid, 64x64 each
    const int srow = lane >> 2;                      // 16 rows per gload
    const int swku = (((lane & 3) ^ ((lane >> 3) & 3)) * 16);   // byte off of global unit
    const uchar_t* gA = A8 + (size_t)(row0 + wid * 32 + srow) * D_ + swku;
    const uchar_t* gB = B8 + (size_t)(col0 + wid * 32 + srow) * D_ + swku;
    f32x4 acc[4][4];
#pragma unroll
    for (int i = 0; i < 4; ++i)
#pragma unroll
        for (int j = 0; j < 4; ++j) acc[i][j] = (f32x4){0.f, 0.f, 0.f, 0.f};
    const int cl = lane & 15, q = lane >> 4;
    const int cv = (cl >> 1) & 3;

    auto STAGE = [&](int buf, int k0) {              // k0 in bytes (fp8 elems)
        uchar_t* la = &As[buf][wid * 2048];          // 32 rows x 64B per wave
        uchar_t* lb = &Bs[buf][wid * 2048];
        gload16b(gA + k0, la);
        gload16b(gA + k0 + 16 * D_, la + 1024);
        gload16b(gB + k0, lb);
        gload16b(gB + k0 + 16 * D_, lb + 1024);
    };
    auto COMPUTE = [&](int buf) {
#pragma unroll
        for (int ks = 0; ks < 2; ++ks) {             // K=64 tile = 2 x (K=32 MFMA)
            const int c = ks * 4 + q;
            const int co8 = (((c >> 1) ^ cv) * 16) + ((c & 1) * 8);
            fp8x8 af[4], bv[4];
#pragma unroll
            for (int i = 0; i < 4; ++i)
                af[i] = *(const fp8x8*)&As[buf][(wr * 64 + i * 16 + cl) * 64 + co8];
#pragma unroll
            for (int j = 0; j < 4; ++j)
                bv[j] = *(const fp8x8*)&Bs[buf][(wc * 64 + j * 16 + cl) * 64 + co8];
            __builtin_amdgcn_s_setprio(1);
#pragma unroll
            for (int i = 0; i < 4; ++i)
#pragma unroll
                for (int j = 0; j < 4; ++j)
                    acc[i][j] = __builtin_amdgcn_mfma_f32_16x16x32_fp8_fp8(af[i], bv[j], acc[i][j], 0, 0, 0);
            __builtin_amdgcn_s_setprio(0);
        }
    };

    const int NT = D_ / 64;                 // 10
    STAGE(0, 0); STAGE(1, 64);
    int cur = 0;
    for (int tl = 0; tl < NT - 1; ++tl) {
        VMCNT(4); S_BARRIER();              // tile tl landed; tl+1 (4 loads) in flight
        COMPUTE(cur);
        S_BARRIER();
        if (tl + 2 < NT) STAGE(cur, (tl + 2) * 64);
        cur ^= 1;
    }
    VMCNT(0); S_BARRIER();
    COMPUTE(cur);

    const float inv_sc = 1.0f / 128.0f;     // 1/(sA*sB)
#pragma unroll
    for (int i = 0; i < 4; ++i) {
#pragma unroll
        for (int ee = 0; ee < 4; ++ee) {
            int r = row0 + wr * 64 + i * 16 + q * 4 + ee;
            int n = r % NANCH;
            uchar_t* orow = E8 + (size_t)r * NANCHP;
#pragma unroll
            for (int j = 0; j < 4; ++j) {
                int m = col0 + wc * 64 + j * 16 + cl;
                if (m < NM)
                    orow[m + (m >= n)] = f2fp8(__expf(acc[i][j][ee] * inv_sc + attn_b[m]) * 16.f);
            }
        }
    }
}

// ============ normalize: attn[r][:] = E8/sum(E8) (fp32); rsum[r] = sum(E8) ============
__global__ __launch_bounds__(256) void normalize_k(const uchar_t* __restrict__ E8,
    float* __restrict__ attn, float* __restrict__ rsum)
{
    const int r = blockIdx.x;
    float* row = attn + (size_t)r * NANCH;
    const uchar_t* row8 = E8 + (size_t)r * NANCHP;
    const int t = threadIdx.x;
    __shared__ float red[4];
    float vals[16];                           // static-indexed -> VGPRs
    float s = 0.f;
    if (t < 174) {                            // 2784 = 174 x 16 fp8
        u32x4 u = *(const u32x4*)&row8[16 * t];   // 16B load: 16 fp8
#pragma unroll
        for (int k = 0; k < 4; ++k) {
            uint32 w = (k == 0) ? u.x : (k == 1) ? u.y : (k == 2) ? u.z : u.w;
            vals[4 * k + 0] = fp82f(w & 0xffu);
            vals[4 * k + 1] = fp82f((w >> 8) & 0xffu);
            vals[4 * k + 2] = fp82f((w >> 16) & 0xffu);
            vals[4 * k + 3] = fp82f(w >> 24);
        }
#pragma unroll
        for (int k = 0; k < 16; ++k) s += vals[k];
    } else {
#pragma unroll
        for (int k = 0; k < 16; ++k) vals[k] = 0.f;
    }
    for (int off = 32; off; off >>= 1) s += __shfl_down(s, off);
    if ((t & 63) == 0) red[t >> 6] = s;
    __syncthreads();
    s = red[0] + red[1] + red[2] + red[3];
    float inv = 1.0f / s;                     // x16 scale cancels in E8/sum(E8)
    if (t == 0) rsum[r] = s;
    if (t < 174) {
#pragma unroll
        for (int k = 0; k < 4; ++k) {
            float4 w0 = make_float4(vals[4 * k] * inv, vals[4 * k + 1] * inv,
                                    vals[4 * k + 2] * inv, vals[4 * k + 3] * inv);
            *(float4*)&row[16 * t + 4 * k] = w0;   // 16B-aligned fp32 stores
        }
    }
}

// ============ G8[b][o][n] = fp8((pf·W1^T)[n][o] * 64)  (W1 = hw16 cols 0..639) ============
__global__ __launch_bounds__(256, 2) void gx_mfma_k(
    const ushort_t* __restrict__ A,   // pf16 [M_][640]
    const ushort_t* __restrict__ W,   // hw16 [128][1280]
    uchar_t* __restrict__ G8)         // [B][128][2816] fp8, values g*64
{
    __shared__ __align__(16) ushort_t As[2][8192];
    __shared__ __align__(16) ushort_t Bs[2][8192];
    const int t = threadIdx.x;
    const int wid = t >> 6, lane = t & 63;
    const int wr = wid >> 1, wc = wid & 1;          // 2x2 wave grid
    const int row0 = blockIdx.x * 128;
    const int r8 = lane >> 3;
    const int ck = (lane & 7) ^ r8;
    const ushort_t* gA = A + (size_t)(row0 + wid * 8 + r8) * D_ + ck * 8;
    const ushort_t* gB = W + (size_t)(wid * 8 + r8) * D2 + ck * 8;
    f32x4 acc[4][4];
#pragma unroll
    for (int i = 0; i < 4; ++i)
#pragma unroll
        for (int j = 0; j < 4; ++j) acc[i][j] = (f32x4){0.f, 0.f, 0.f, 0.f};
    const int cl = lane & 15, q = lane >> 4, cl7 = lane & 7;

    auto STAGE = [&](int buf, int k0) {
        ushort_t* la = &As[buf][wid * 512];
        ushort_t* lb = &Bs[buf][wid * 512];
#pragma unroll
        for (int j = 0; j < 4; ++j) {
            gload16(gA + k0 + (size_t)j * 32 * D_, la + j * 2048);
            gload16(gB + k0 + (size_t)j * 32 * D2, lb + j * 2048);
        }
    };
    auto COMPUTE = [&](int buf) {
#pragma unroll
        for (int ks = 0; ks < 2; ++ks) {
            short8 af[4], bv[4];
            const int co = ((ks * 4 + q) ^ cl7) * 8;
#pragma unroll
            for (int i = 0; i < 4; ++i)
                af[i] = *(const short8*)&As[buf][(wr * 64 + i * 16 + cl) * 64 + co];
#pragma unroll
            for (int j = 0; j < 4; ++j)
                bv[j] = *(const short8*)&Bs[buf][(wc * 64 + j * 16 + cl) * 64 + co];
            __builtin_amdgcn_s_setprio(1);
#pragma unroll
            for (int i = 0; i < 4; ++i)
#pragma unroll
                for (int j = 0; j < 4; ++j)
                    acc[i][j] = __builtin_amdgcn_mfma_f32_16x16x32_bf16(af[i], bv[j], acc[i][j], 0, 0, 0);
            __builtin_amdgcn_s_setprio(0);
        }
    };

    const int NT = D_ / 64;                 // 10
    STAGE(0, 0); STAGE(1, 64);
    int cur = 0;
    for (int tl = 0; tl < NT - 1; ++tl) {
        VMCNT(8); S_BARRIER();
        COMPUTE(cur);
        S_BARRIER();
        if (tl + 2 < NT) STAGE(cur, (tl + 2) * 64);
        cur ^= 1;
    }
    VMCNT(0); S_BARRIER();
    COMPUTE(cur);

#pragma unroll
    for (int i = 0; i < 4; ++i) {
#pragma unroll
        for (int ee = 0; ee < 4; ++ee) {
            int r = row0 + wr * 64 + i * 16 + q * 4 + ee;   // < M_ (174*128 exact)
            int b = r / NANCH, nl = r - b * NANCH;
#pragma unroll
            for (int j = 0; j < 4; ++j) {
                int o = wc * 64 + j * 16 + cl;
                G8[((size_t)b * NO + o) * NANCHP + nl] = f2fp8(acc[i][j][ee] * 64.f);
            }
        }
    }
}

// ============ final (split-K x6): kc 0..3 = E8·G8 fp8 BK=64 (11 tiles each),
//              kc 4..5 = pf·W2^T bf16 BK=32 (10 tiles each) ============
__global__ __launch_bounds__(256, 4) void final_mfma_k(
    const uchar_t* __restrict__ E8,    // [M_+32][2816] fp8 (exp*16)
    const ushort_t* __restrict__ pf16, // [M_][640]
    const uchar_t* __restrict__ G8,    // [B][128][2816] fp8 (g*64)
    const ushort_t* __restrict__ W,    // hw16 [128][1280] (W2 = cols 640..1279)
    float* __restrict__ part)          // [6][M_][128] fp32 partials
{
    __shared__ __align__(16) uchar_t As[2][8192];
    __shared__ __align__(16) uchar_t Bs[2][8192];
    // grid 1056: b=XCD (G8[b] L2-resident), rb=row-slab 0..21, kc=chunk 0..5
    const int b = blockIdx.x & 7;
    const int u = blockIdx.x >> 3;
    const int rb = u % 22, kc = u / 22;
    const int t = threadIdx.x;
    const int wid = t >> 6, lane = t & 63;
    const int wr = wid >> 1, wc = wid & 1;
    const int cl = lane & 15, q = lane >> 4;
    f32x4 acc[4][4];
#pragma unroll
    for (int i = 0; i < 4; ++i)
#pragma unroll
        for (int j = 0; j < 4; ++j) acc[i][j] = (f32x4){0.f, 0.f, 0.f, 0.f};

    if (kc < 4) {
        // ---- fp8 path: E8·G8, BK=64, tiles [kc*11, kc*11+11) of 44 ----
        const int srow = lane >> 2;
        const int swku = (((lane & 3) ^ ((lane >> 3) & 3)) * 16);
        // A rows may over-read past batch end (+32-row pad on E8) -> discarded.
        const size_t arow = (size_t)b * NANCH + rb * 128 + wid * 32 + srow;
        const uchar_t* gA = E8 + arow * NANCHP + swku;
        const uchar_t* gB = G8 + ((size_t)b * NO + wid * 32 + srow) * NANCHP + swku;
        const int cv = (cl >> 1) & 3;
        auto STAGE = [&](int buf, int gt) {
            const int k0 = gt * 64;
            uchar_t* la = &As[buf][wid * 2048];
            uchar_t* lb = &Bs[buf][wid * 2048];
            gload16b(gA + k0, la);
            gload16b(gA + k0 + (size_t)16 * NANCHP, la + 1024);
            gload16b(gB + k0, lb);
            gload16b(gB + k0 + (size_t)16 * NANCHP, lb + 1024);
        };
        auto COMPUTE = [&](int buf) {
#pragma unroll
            for (int ks = 0; ks < 2; ++ks) {
                const int c = ks * 4 + q;
                const int co8 = (((c >> 1) ^ cv) * 16) + ((c & 1) * 8);
                fp8x8 af[4], bv[4];
#pragma unroll
                for (int i = 0; i < 4; ++i)
                    af[i] = *(const fp8x8*)&As[buf][(wr * 64 + i * 16 + cl) * 64 + co8];
#pragma unroll
                for (int j = 0; j < 4; ++j)
                    bv[j] = *(const fp8x8*)&Bs[buf][(wc * 64 + j * 16 + cl) * 64 + co8];
                __builtin_amdgcn_s_setprio(1);
#pragma unroll
                for (int i = 0; i < 4; ++i)
#pragma unroll
                    for (int j = 0; j < 4; ++j)
                        acc[i][j] = __builtin_amdgcn_mfma_f32_16x16x32_fp8_fp8(af[i], bv[j], acc[i][j], 0, 0, 0);
                __builtin_amdgcn_s_setprio(0);
            }
        };
        const int g0 = kc * 11, NT = 11;
        STAGE(0, g0); STAGE(1, g0 + 1);
        int cur = 0;
        for (int tl = 0; tl < NT - 1; ++tl) {
            VMCNT(4); S_BARRIER();
            COMPUTE(cur);
            S_BARRIER();
            if (tl + 2 < NT) STAGE(cur, g0 + tl + 2);
            cur ^= 1;
        }
        VMCNT(0); S_BARRIER();
        COMPUTE(cur);
    } else {
        // ---- bf16 path: pf·W2^T, BK=32, tiles [(kc-4)*10, +10) of 20 ----
        const int srow = lane >> 2;
        const int swk  = (((lane & 3) ^ ((lane >> 3) & 3)) * 8);
        // pf16 over-read (+32 rows) lands in pf8 buffer -> finite, discarded.
        const size_t arow = (size_t)b * NANCH + rb * 128 + wid * 32 + srow;
        const ushort_t* gAp = pf16 + arow * D_ + swk;
        const ushort_t* gBw = W + (size_t)(wid * 32 + srow) * D2 + D_ + swk;
        const int ra = wr * 64 + cl, rbb = wc * 64 + cl;
        const int aoff = ra * 32 + ((q ^ ((ra >> 1) & 3)) * 8);
        const int boff = rbb * 32 + ((q ^ ((rbb >> 1) & 3)) * 8);
        auto STAGE = [&](int buf, int gt) {
            const int kk = gt * 32;
            ushort_t* la = (ushort_t*)&As[buf][wid * 2048];
            ushort_t* lb = (ushort_t*)&Bs[buf][wid * 2048];
            gload16(gAp + kk, la);
            gload16(gAp + kk + (size_t)16 * D_, la + 512);
            gload16(gBw + kk, lb);
            gload16(gBw + kk + (size_t)16 * D2, lb + 512);
        };
        auto COMPUTE = [&](int buf) {
            const ushort_t* As16 = (const ushort_t*)As[buf];
            const ushort_t* Bs16 = (const ushort_t*)Bs[buf];
            short8 af[4], bv[4];
#pragma unroll
            for (int i = 0; i < 4; ++i) af[i] = *(const short8*)&As16[aoff + i * 512];
#pragma unroll
            for (int j = 0; j < 4; ++j) bv[j] = *(const short8*)&Bs16[boff + j * 512];
            __builtin_amdgcn_s_setprio(1);
#pragma unroll
            for (int i = 0; i < 4; ++i)
#pragma unroll
                for (int j = 0; j < 4; ++j)
                    acc[i][j] = __builtin_amdgcn_mfma_f32_16x16x32_bf16(af[i], bv[j], acc[i][j], 0, 0, 0);
            __builtin_amdgcn_s_setprio(0);
        };
        const int g0 = (kc - 4) * 10, NT = 10;
        STAGE(0, g0); STAGE(1, g0 + 1);
        int cur = 0;
        for (int tl = 0; tl < NT - 1; ++tl) {
            VMCNT(4); S_BARRIER();
            COMPUTE(cur);
            S_BARRIER();
            if (tl + 2 < NT) STAGE(cur, g0 + tl + 2);
            cur ^= 1;
        }
        VMCNT(0); S_BARRIER();
        COMPUTE(cur);
    }

    float* pout = part + (size_t)kc * M_ * NO;
#pragma unroll
    for (int i = 0; i < 4; ++i) {
#pragma unroll
        for (int ee = 0; ee < 4; ++ee) {
            int nl = rb * 128 + wr * 64 + i * 16 + q * 4 + ee;
            if (nl < NANCH) {
                int r = b * NANCH + nl;
#pragma unroll
                for (int j = 0; j < 4; ++j) {
                    int oo = wc * 64 + j * 16 + cl;
                    pout[(size_t)r * NO + oo] = acc[i][j][ee];
                }
            }
        }
    }
}

// ============ reduce: out = (p0..p3)/(64*rsum) + p4 + p5 + bias; heads epilogue ============
// scales: p_fp8 = (16E)·(64G) = 1024·E·G ; rsum = 16·sum(E)  =>  /(64·rsum) exact.
__global__ __launch_bounds__(256) void reduce_heads_k(
    const float* __restrict__ part,    // [6][M_][128]
    const float* __restrict__ rsum,
    const float* __restrict__ cls_b, const float* __restrict__ reg_b,
    const float* __restrict__ anchors,
    float* __restrict__ cls_out, float* __restrict__ lanes)
{
    int t = blockIdx.x * 256 + threadIdx.x;
    if (t >= M_ * 80) return;
    int r = t / 80, oo = t - r * 80;
    int nl = r % NANCH;
    if (oo < 75) {
        float inv = 1.0f / (64.0f * rsum[r]);
        size_t base = (size_t)r * NO + oo, st = (size_t)M_ * NO;
        float v = ((part[base] + part[base + st]) + (part[base + 2 * st] + part[base + 3 * st])) * inv
                + part[base + 4 * st] + part[base + 5 * st];
        if (oo < 2) {
            cls_out[(size_t)r * 2 + oo] = v + cls_b[oo];
        } else {
            int qq = oo - 2;
            int c = 4 + qq;
            float res = v + reg_b[qq];
            if (qq > 0) res += anchors[(size_t)nl * ALEN + c];
            lanes[(size_t)r * ALEN + c] = res;
        }
    } else if (oo < 79) {
        int c = oo - 75;                      // lanes cols 0..3 = anchors
        lanes[(size_t)r * ALEN + c] = anchors[(size_t)nl * ALEN + c];
    }
}

extern "C" void kernel_launch(void* const* d_in, const int* in_sizes, int n_in,
                              void* d_out, int out_size, void* d_ws, size_t ws_size,
                              hipStream_t stream)
{
    (void)in_sizes; (void)n_in; (void)out_size; (void)ws_size;
    const float* x       = (const float*)d_in[0];
    const float* conv_w  = (const float*)d_in[1];
    const float* conv_b  = (const float*)d_in[2];
    const float* attn_w  = (const float*)d_in[3];
    const float* attn_b  = (const float*)d_in[4];
    const float* cls_w   = (const float*)d_in[5];
    const float* cls_b   = (const float*)d_in[6];
    const float* reg_w   = (const float*)d_in[7];
    const float* reg_b   = (const float*)d_in[8];
    const float* anchors = (const float*)d_in[9];
    const int*   cut_xs  = (const int*)d_in[10];
    const unsigned char* invalid = (const unsigned char*)d_in[11];

    float* out     = (float*)d_out;
    float* cls_out = out;
    float* lanes   = out + (size_t)M_ * 2;
    float* attn    = out + (size_t)M_ * 2 + (size_t)M_ * ALEN;

    // workspace layout (~180 MB)
    char* w = (char*)d_ws;
    float* feat      = (float*)w;    w += (size_t)B_ * CF * HFM * WFM * 4;       // 512 KB
    ushort_t* pf16   = (ushort_t*)w; w += (size_t)M_ * D_ * 2;                   // 28.5 MB
    uchar_t* pf8     = (uchar_t*)w;  w += (size_t)M_ * D_;                       // 14.3 MB (absorbs pf16 over-read)
    uchar_t* aw8     = (uchar_t*)w;  w += (size_t)NMPAD * D_;                    // 1.8 MB
    ushort_t* hw16   = (ushort_t*)w; w += (size_t)128 * D2 * 2;                  // 320 KB
    uchar_t* G8      = (uchar_t*)w;  w += (size_t)B_ * NO * NANCHP;              // 2.9 MB
    float* part      = (float*)w;    w += (size_t)6 * M_ * NO * 4;               // 68.4 MB
    float* rsum      = (float*)w;    w += (size_t)M_ * 4;                        // 89 KB
    uchar_t* E8      = (uchar_t*)w;  w += (size_t)(M_ + 32) * NANCHP;            // 62.8 MB

    conv_feat_k<<<(B_ * CF * HFM * WFM + 255) / 256, 256, 0, stream>>>(x, conv_w, conv_b, feat);
    gather_pf_k<<<(int)(((long long)M_ * D_ + 255) / 256), 256, 0, stream>>>(feat, cut_xs, invalid, pf16, pf8);
    prep_all_k<<<(PREP_TOT + 255) / 256, 256, 0, stream>>>(attn_w, cls_w, reg_w,
                                                           aw8, hw16, G8, E8);

    gx_mfma_k<<<M_ / 128, 256, 0, stream>>>(pf16, hw16, G8);

    scores_mfma_k<<<dim3(174 * 22), 256, 0, stream>>>(pf8, aw8, attn_b, E8);
    normalize_k<<<M_, 256, 0, stream>>>(E8, attn, rsum);

    final_mfma_k<<<dim3(6 * 22 * B_), 256, 0, stream>>>(E8, pf16, G8, hw16, part);
    reduce_heads_k<<<(M_ * 80 + 255) / 256, 256, 0, stream>>>(part, rsum, cls_b, reg_b,
                                                              anchors, cls_out, lanes);
}